// Round 7
// baseline (436.799 us; speedup 1.0000x reference)
//
#include <hip/hip_runtime.h>
#include <stdint.h>

// KNN K=16 over x (B=2, N=8192, D=64) f32. Output int32 (2,B,N,K): nn_idx, center_idx.
// Pipeline: split_k (bf16 hi + residual norms) -> red_k (batch maxima) -> tau_p
// (MFMA hi-only min-ladders over a 4096-sample, register-double-buffered
// streaming) -> tau_m (merge -> per-query threshold with PROVABLE Cauchy-Schwarz
// slop) -> filter_k (MFMA hi-only distance, BARRIER-FREE, register-double-
// buffered B-fragment pipeline, accepts via LDS atomics) -> rerank_k (exact f64,
// 32-VGPR latency-lean form; single round for ~all queries).
// R6 evidence: filter_k was latency-bound (MfmaUtil 14%, VALUBusy 24%, occ 35%,
// VGPR=64 -> compiler allocated NO prefetch regs). Explicit 1-deep B-fragment +
// norm prefetch per chunk overlaps L2 latency with MFMA/epilogue.
// Bound: |key_approx - key_true| <= 2(n_q E + e_q H) with e_i MEASURED in split_k,
// E = max e, H = Nmax + E. tau = u16_approx + 2*slop provably keeps all true
// top-16 (pigeonhole: u16 = 16th smallest of 128 column-minima over the
// 4096-sample >= sample-d16 >= population-d16).
constexpr int N_    = 8192;
constexpr int D_    = 64;
constexpr int K_    = 16;
constexpr int NQ    = 16384;          // 2*8192
constexpr int MS    = 8;              // m-superblocks per batch (1024 m each)
constexpr int CAPB  = 40;             // survivor cap per (query, superblock)

typedef __attribute__((ext_vector_type(8))) short bf16x8;
typedef __attribute__((ext_vector_type(4))) float f32x4;

template<int JN>
__device__ __forceinline__ void topk_insertf(float (&key)[JN], float nk) {
    if (nk < key[JN - 1]) {
        bool c[JN];
#pragma unroll
        for (int j = 0; j < JN; ++j) c[j] = nk < key[j];
#pragma unroll
        for (int j = JN - 1; j >= 1; --j)
            key[j] = c[j - 1] ? key[j - 1] : (c[j] ? nk : key[j]);
        key[0] = c[0] ? nk : key[0];
    }
}

__device__ __forceinline__ unsigned short bf16_rne(float f) {
    uint32_t u = __float_as_uint(f);
    return (unsigned short)((u + 0x7FFFu + ((u >> 16) & 1u)) >> 16);   // no NaN in data
}

// K1: bf16 hi split + true squared norms + residual norms. 16 lanes/row. grid=1024.
__global__ void __launch_bounds__(256) split_k(const float* __restrict__ x,
                                               unsigned short* __restrict__ xh,
                                               float* __restrict__ nrm,
                                               float* __restrict__ eres) {
    const int t = blockIdx.x * 256 + (int)threadIdx.x;    // one float4 per thread
    const int row = t >> 4, seg = t & 15;
    const float4 v = reinterpret_cast<const float4*>(x)[t];
    float f[4] = {v.x, v.y, v.z, v.w};
    unsigned short h[4];
    float sq = 0.f, esq = 0.f;
#pragma unroll
    for (int j = 0; j < 4; ++j) {
        sq = fmaf(f[j], f[j], sq);
        h[j] = bf16_rne(f[j]);
        float hf = __uint_as_float((uint32_t)h[j] << 16);
        float r  = f[j] - hf;
        esq = fmaf(r, r, esq);
    }
    sq  += __shfl_xor(sq, 1, 16);  sq  += __shfl_xor(sq, 2, 16);
    sq  += __shfl_xor(sq, 4, 16);  sq  += __shfl_xor(sq, 8, 16);
    esq += __shfl_xor(esq, 1, 16); esq += __shfl_xor(esq, 2, 16);
    esq += __shfl_xor(esq, 4, 16); esq += __shfl_xor(esq, 8, 16);
    if (seg == 0) { nrm[row] = sq; eres[row] = sqrtf(esq); }
    ushort4 hv = {h[0], h[1], h[2], h[3]};
    reinterpret_cast<ushort4*>(xh)[t] = hv;
}

// K1b: per-batch maxima: EH[b] = {Nmax, Emax} (inflated for f32 rounding). grid=2.
__global__ void __launch_bounds__(256) red_k(const float* __restrict__ nrm,
                                             const float* __restrict__ eres,
                                             float* __restrict__ EH) {
    __shared__ float mbuf[8];
    const int b = (int)blockIdx.x, tid = (int)threadIdx.x;
    float mn = 0.f, me = 0.f;
    for (int i = tid; i < N_; i += 256) {
        mn = fmaxf(mn, nrm[b * N_ + i]);
        me = fmaxf(me, eres[b * N_ + i]);
    }
#pragma unroll
    for (int s = 1; s < 64; s <<= 1) {
        mn = fmaxf(mn, __shfl_xor(mn, s, 64));
        me = fmaxf(me, __shfl_xor(me, s, 64));
    }
    const int w = tid >> 6;
    if ((tid & 63) == 0) { mbuf[w * 2] = mn; mbuf[w * 2 + 1] = me; }
    __syncthreads();
    if (tid == 0) {
        for (int i = 1; i < 4; ++i) {
            mn = fmaxf(mn, mbuf[i * 2]); me = fmaxf(me, mbuf[i * 2 + 1]);
        }
        EH[b * 2]     = sqrtf(mn) * 1.0002f + 1e-6f;      // Nmax upper bound
        EH[b * 2 + 1] = me * 1.0002f + 1e-7f;             // Emax upper bound
    }
}

// K2a: MFMA tau partials over a 4096-sample, register-double-buffered streaming.
// Block = 128q x 1024 samples (quarter sh), 16 chunks of 64. Next chunk's B
// frags + norms prefetched into regs during current chunk's MFMA/epilogue.
// grid = 128 q-tiles x 4 quarters = 512.
__global__ void __launch_bounds__(256, 4) tau_p(const unsigned short* __restrict__ xh,
                                                const float* __restrict__ nrm,
                                                float* __restrict__ part) {
    __shared__ alignas(16) float nrmS[1024];                // 4 KB sample norms
    const int tid = (int)threadIdx.x;
    const int bid = (int)blockIdx.x;
    const int qt  = bid >> 2, sh = bid & 3;
    const int q0g = qt * 128;
    const int b   = q0g >> 13;                              // uniform (128 | 8192)
    const int q0l = q0g & (N_ - 1);
    const int s0  = sh * 1024;
    const unsigned short* __restrict__ xhb = xh + (size_t)b * N_ * D_;
    const float* __restrict__ nb = nrm + b * N_;
    const int w = tid >> 6, lane = tid & 63;
    const int wq = w >> 1, wm = w & 1;                      // 64q x 32s wave subtile
    const int l15 = lane & 15, quad = lane >> 4;

    *(float4*)(nrmS + tid * 4) = *(const float4*)(nb + s0 + tid * 4);

    bf16x8 Af[2][4];                                        // A frags from global
#pragma unroll
    for (int half = 0; half < 2; ++half) {
        const int eo = (half * 4 + quad) * 8;               // element offset in row
#pragma unroll
        for (int tm = 0; tm < 4; ++tm)
            Af[half][tm] = *(const bf16x8*)(xhb + (size_t)(q0l + wq * 64 + tm * 16 + l15) * D_ + eo);
    }
    bf16x8 Bf[2][2];                                        // chunk-0 B frags (pre-barrier)
#pragma unroll
    for (int half = 0; half < 2; ++half) {
        const int eo = (half * 4 + quad) * 8;
#pragma unroll
        for (int tn = 0; tn < 2; ++tn)
            Bf[half][tn] = *(const bf16x8*)(xhb + (size_t)(s0 + wm * 32 + tn * 16 + l15) * D_ + eo);
    }
    float lad[16];
#pragma unroll
    for (int j = 0; j < 16; ++j) lad[j] = __builtin_inff();
    __syncthreads();                                        // nrmS visible

    float nm0 = nrmS[wm * 32 + l15];
    float nm1 = nrmS[wm * 32 + 16 + l15];
#pragma unroll
    for (int mc = 0; mc < 16; ++mc) {
        bf16x8 Bn[2][2];                                    // prefetch next chunk
        float nn0 = 0.f, nn1 = 0.f;
        if (mc < 15) {
            const unsigned short* Bb = xhb + (size_t)(s0 + (mc + 1) * 64) * D_;
#pragma unroll
            for (int half = 0; half < 2; ++half) {
                const int eo = (half * 4 + quad) * 8;
#pragma unroll
                for (int tn = 0; tn < 2; ++tn)
                    Bn[half][tn] = *(const bf16x8*)(Bb + (size_t)(wm * 32 + tn * 16 + l15) * D_ + eo);
            }
            nn0 = nrmS[(mc + 1) * 64 + wm * 32 + l15];
            nn1 = nrmS[(mc + 1) * 64 + wm * 32 + 16 + l15];
        }
        f32x4 acc[4][2] = {};
#pragma unroll
        for (int half = 0; half < 2; ++half)
#pragma unroll
            for (int tm = 0; tm < 4; ++tm)
#pragma unroll
                for (int tn = 0; tn < 2; ++tn)
                    acc[tm][tn] = __builtin_amdgcn_mfma_f32_16x16x32_bf16(Af[half][tm], Bf[half][tn], acc[tm][tn], 0, 0, 0);
        // epilogue: C/D col=lane&15 (sample), row=quad*4+reg (q); depth-1 min
#pragma unroll
        for (int tn = 0; tn < 2; ++tn) {
            const float nm = tn ? nm1 : nm0;
#pragma unroll
            for (int tm = 0; tm < 4; ++tm)
#pragma unroll
                for (int reg = 0; reg < 4; ++reg)
                    lad[tm * 4 + reg] = fminf(lad[tm * 4 + reg],
                                              fmaf(-2.f, acc[tm][tn][reg], nm));
        }
        if (mc < 15) {
#pragma unroll
            for (int half = 0; half < 2; ++half)
#pragma unroll
                for (int tn = 0; tn < 2; ++tn) Bf[half][tn] = Bn[half][tn];
            nm0 = nn0; nm1 = nn1;
        }
    }
    // part[q][128]: offset = sh*32 + wm*16 + l15
#pragma unroll
    for (int tm = 0; tm < 4; ++tm)
#pragma unroll
        for (int reg = 0; reg < 4; ++reg) {
            const int q = q0g + wq * 64 + tm * 16 + quad * 4 + reg;
            part[(size_t)q * 128 + sh * 32 + wm * 16 + l15] = lad[tm * 4 + reg];
        }
}

// K2b: merge 128 partials/query -> tau with provable slop. grid = NQ/64 = 256.
__global__ void __launch_bounds__(64) tau_m(const float* __restrict__ part,
                                            const float* __restrict__ nrm,
                                            const float* __restrict__ eres,
                                            const float* __restrict__ EH,
                                            float* __restrict__ tau) {
    const int q = blockIdx.x * 64 + (int)threadIdx.x;
    const int b = q >> 13;
    const float4* p = reinterpret_cast<const float4*>(part + (size_t)q * 128);
    float key[K_];
#pragma unroll
    for (int j = 0; j < K_; ++j) key[j] = __builtin_inff();
    for (int i = 0; i < 32; ++i) {
        float4 v = p[i];
        topk_insertf<K_>(key, v.x); topk_insertf<K_>(key, v.y);
        topk_insertf<K_>(key, v.z); topk_insertf<K_>(key, v.w);
    }
    const float Nmax = EH[b * 2], Emax = EH[b * 2 + 1];
    const float H = Nmax + Emax;                            // >= max ||xh_m||
    const float nq = sqrtf(nrm[q]) * 1.0001f, eq = eres[q];
    tau[q] = key[15] + 4.f * (nq * Emax + eq * H) + 6e-3f;  // 2*s_q + f32 fudge
}

// K3: MFMA filter, BARRIER-FREE, register-double-buffered. Block = 128q x 1024m,
// 16 chunks of 64m; next chunk's B frags (4x16B) + 2 norms prefetched into regs
// before current chunk's MFMA/epilogue -> L2 latency overlaps compute.
// Accepts -> LDS per-query lists (DS atomics). grid = 2*64*8 = 1024 blocks.
__global__ void __launch_bounds__(256, 4) filter_k(const unsigned short* __restrict__ xh,
                                                   const float* __restrict__ nrm,
                                                   const float* __restrict__ tau,
                                                   unsigned short* __restrict__ cnt_pb,
                                                   unsigned short* __restrict__ buf2) {
    __shared__ alignas(16) float nrmS[1024];                // 4 KB superblock norms
    __shared__ unsigned short lists[128 * CAPB];            // 10 KB
    __shared__ unsigned int cntL[128];
    const int tid = (int)threadIdx.x;
    const int bid = (int)blockIdx.x;
    const int b  = bid >> 9;
    const int qt = (bid >> 3) & 63;
    const int ms = bid & 7;
    const int q0 = qt * 128;
    const unsigned short* __restrict__ xhb = xh + (size_t)b * N_ * D_;
    const float* __restrict__ nb = nrm + b * N_;
    const int w = tid >> 6, lane = tid & 63;
    const int wq = w >> 1, wm = w & 1;                      // 64q x 32m wave subtile
    const int l15 = lane & 15, quad = lane >> 4;

    *(float4*)(nrmS + tid * 4) = *(const float4*)(nb + ms * 1024 + tid * 4);
    if (tid < 128) cntL[tid] = 0;

    bf16x8 Af[2][4];                                        // A frags from global
#pragma unroll
    for (int half = 0; half < 2; ++half) {
        const int eo = (half * 4 + quad) * 8;
#pragma unroll
        for (int tm = 0; tm < 4; ++tm)
            Af[half][tm] = *(const bf16x8*)(xhb + (size_t)(q0 + wq * 64 + tm * 16 + l15) * D_ + eo);
    }
    bf16x8 Bf[2][2];                                        // chunk-0 B frags (pre-barrier)
#pragma unroll
    for (int half = 0; half < 2; ++half) {
        const int eo = (half * 4 + quad) * 8;
#pragma unroll
        for (int tn = 0; tn < 2; ++tn)
            Bf[half][tn] = *(const bf16x8*)(xhb + (size_t)(ms * 1024 + wm * 32 + tn * 16 + l15) * D_ + eo);
    }
    f32x4 t4v[4];
#pragma unroll
    for (int tm = 0; tm < 4; ++tm)
        t4v[tm] = *(const f32x4*)(tau + (b << 13) + q0 + wq * 64 + tm * 16 + quad * 4);
    __syncthreads();                                        // nrmS visible

    float nm0 = nrmS[wm * 32 + l15];
    float nm1 = nrmS[wm * 32 + 16 + l15];
#pragma unroll
    for (int mc = 0; mc < 16; ++mc) {
        bf16x8 Bn[2][2];                                    // prefetch next chunk
        float nn0 = 0.f, nn1 = 0.f;
        if (mc < 15) {
            const unsigned short* Bb = xhb + (size_t)(ms * 1024 + (mc + 1) * 64) * D_;
#pragma unroll
            for (int half = 0; half < 2; ++half) {
                const int eo = (half * 4 + quad) * 8;
#pragma unroll
                for (int tn = 0; tn < 2; ++tn)
                    Bn[half][tn] = *(const bf16x8*)(Bb + (size_t)(wm * 32 + tn * 16 + l15) * D_ + eo);
            }
            nn0 = nrmS[(mc + 1) * 64 + wm * 32 + l15];
            nn1 = nrmS[(mc + 1) * 64 + wm * 32 + 16 + l15];
        }
        f32x4 acc[4][2] = {};
#pragma unroll
        for (int half = 0; half < 2; ++half)
#pragma unroll
            for (int tm = 0; tm < 4; ++tm)
#pragma unroll
                for (int tn = 0; tn < 2; ++tn)
                    acc[tm][tn] = __builtin_amdgcn_mfma_f32_16x16x32_bf16(Af[half][tm], Bf[half][tn], acc[tm][tn], 0, 0, 0);
        // epilogue: C/D col=lane&15 (m), row=quad*4+reg (q); accept key <= tau
#pragma unroll
        for (int tn = 0; tn < 2; ++tn) {
            const int mloc = mc * 64 + wm * 32 + tn * 16 + l15;
            const float nm = tn ? nm1 : nm0;
            const unsigned short mid = (unsigned short)(ms * 1024 + mloc);
#pragma unroll
            for (int tm = 0; tm < 4; ++tm)
#pragma unroll
                for (int reg = 0; reg < 4; ++reg) {
                    float keyf = fmaf(-2.f, acc[tm][tn][reg], nm);
                    if (keyf <= t4v[tm][reg]) {             // rare (~0.4%)
                        int ql = wq * 64 + tm * 16 + quad * 4 + reg;
                        unsigned pos = atomicAdd(&cntL[ql], 1u);    // LDS atomic
                        if (pos < CAPB) lists[ql * CAPB + pos] = mid;
                    }
                }
        }
        if (mc < 15) {
#pragma unroll
            for (int half = 0; half < 2; ++half)
#pragma unroll
                for (int tn = 0; tn < 2; ++tn) Bf[half][tn] = Bn[half][tn];
            nm0 = nn0; nm1 = nn1;
        }
    }
    __syncthreads();                                        // all waves' accepts visible
    if (tid < 128) {                                        // flush to fixed slots
        const int q = (b << 13) + q0 + tid;
        unsigned cn = cntL[tid]; cn = cn < CAPB ? cn : CAPB;
        cnt_pb[(size_t)q * MS + ms] = (unsigned short)cn;
        unsigned short* dst = buf2 + ((size_t)q * MS + ms) * CAPB;
        for (unsigned i = 0; i < cn; ++i) dst[i] = lists[tid * CAPB + i];
    }
}

// K4: exact f64 rerank, wave-per-query (32-VGPR latency-lean form; occupancy is
// the binding constraint). With the 4096-sample tau, total <= 64 for ~all
// queries -> single gather+f64+bitonic round. block 256 = 4 waves; grid = 4096.
__global__ void __launch_bounds__(256) rerank_k(const float* __restrict__ x,
                                                const unsigned short* __restrict__ cnt_pb,
                                                const unsigned short* __restrict__ buf2,
                                                int* __restrict__ out) {
    __shared__ float Qs[4 * 64];                           // 1 KB query rows
    __shared__ unsigned short ids[4 * MS * CAPB];          // 2.5 KB compacted survivors
    const int tid = (int)threadIdx.x;
    const int w = tid >> 6, lane = tid & 63;
    const int q = blockIdx.x * 4 + w;
    const int b = q >> 13, n = q & (N_ - 1);
    const float* __restrict__ xb = x + (size_t)b * N_ * D_;
    Qs[w * 64 + lane] = xb[(size_t)n * D_ + lane];

    int off[MS + 1]; off[0] = 0;                           // all lanes compute same
#pragma unroll
    for (int ms = 0; ms < MS; ++ms) {
        int c = (int)cnt_pb[(size_t)q * MS + ms]; c = c < CAPB ? c : CAPB;
        off[ms + 1] = off[ms] + c;
    }
    const int total = off[MS];                             // >= 16 guaranteed (true top-16 pass)
    for (int idx = lane; idx < total; idx += 64) {         // compact ids into LDS
        int ms = 0;
#pragma unroll
        for (int t = 1; t < MS; ++t) ms += (idx >= off[t]) ? 1 : 0;
        ids[(w * MS) * CAPB + idx] = buf2[((size_t)q * MS + ms) * CAPB + (idx - off[ms])];
    }
    __syncthreads();

    unsigned long long v = ~0ull;
    int consumed = 0;
    bool first = true;
    while (first || consumed < total) {
        const int myIdx = first ? lane : consumed + lane - 16;
        const bool take = (first || lane >= 16) && myIdx < total;
        unsigned long long nk = ~0ull;
        if (take) {
            const int id = (int)ids[(w * MS) * CAPB + myIdx];
            const float* __restrict__ crow = xb + (size_t)id * D_;
            double a0 = 0.0, a1 = 0.0, a2 = 0.0, a3 = 0.0;
#pragma unroll
            for (int j = 0; j < 16; ++j) {
                const float4 c  = *(const float4*)(crow + j * 4);        // per-lane gather
                const float4 qv = *(const float4*)(Qs + w * 64 + j * 4); // uniform -> broadcast
                double d0 = (double)qv.x - (double)c.x; a0 = fma(d0, d0, a0);
                double d1 = (double)qv.y - (double)c.y; a1 = fma(d1, d1, a1);
                double d2 = (double)qv.z - (double)c.z; a2 = fma(d2, d2, a2);
                double d3 = (double)qv.w - (double)c.w; a3 = fma(d3, d3, a3);
            }
            double s = (a0 + a1) + (a2 + a3);
            // s >= 0 -> f64 bits order-preserving; low 13 mantissa bits carry the id
            // for exact (dist, id) lexicographic compare (ties -> lower id).
            nk = ((unsigned long long)__double_as_longlong(s) & ~0x1FFFull) | (unsigned)id;
        }
        if (first || lane >= 16) v = nk;                   // lanes 0-15 keep running top-16
        // 64-lane bitonic sort ascending (21 steps)
#pragma unroll
        for (int k = 2; k <= 64; k <<= 1)
#pragma unroll
            for (int j = k >> 1; j > 0; j >>= 1) {
                unsigned long long o = __shfl_xor(v, j, 64);
                const bool keepmin = (((lane & k) == 0) == ((lane & j) == 0));
                unsigned long long mn = v < o ? v : o;
                unsigned long long mx = v < o ? o : v;
                v = keepmin ? mn : mx;
            }
        consumed += first ? 64 : 48;
        first = false;
    }
    if (lane < K_) {
        out[(size_t)q * K_ + lane]                   = (int)(v & 0x1FFFull);  // nn_idx
        out[(size_t)NQ * K_ + (size_t)q * K_ + lane] = n;                     // center_idx
    }
}

extern "C" void kernel_launch(void* const* d_in, const int* in_sizes, int n_in,
                              void* d_out, int out_size, void* d_ws, size_t ws_size,
                              hipStream_t stream) {
    const float* x = (const float*)d_in[0];
    int* out = (int*)d_out;
    char* ws = (char*)d_ws;
    float*          nrm    = (float*)ws;                          //  64 KB @ 0
    float*          tau    = (float*)(ws + (64 << 10));           //  64 KB
    float*          eres   = (float*)(ws + (128 << 10));          //  64 KB
    float*          EH     = (float*)(ws + (192 << 10));          //  16 B
    unsigned short* cnt_pb = (unsigned short*)(ws + (256 << 10)); // 256 KB
    unsigned short* xh     = (unsigned short*)(ws + (1 << 20));   //   2 MB
    unsigned short* buf2   = (unsigned short*)(ws + (5 << 20));   // 10.5 MB (16384*8*40*2)
    float*          part   = (float*)(ws + (5 << 20));            //   8 MB, ALIASES buf2:
    // part is written by tau_p and fully consumed by tau_m BEFORE filter_k writes buf2.

    hipLaunchKernelGGL(split_k,  dim3(1024), dim3(256), 0, stream, x, xh, nrm, eres);
    hipLaunchKernelGGL(red_k,    dim3(2),    dim3(256), 0, stream, nrm, eres, EH);
    hipLaunchKernelGGL(tau_p,    dim3(512),  dim3(256), 0, stream, xh, nrm, part);
    hipLaunchKernelGGL(tau_m,    dim3(256),  dim3(64),  0, stream, part, nrm, eres, EH, tau);
    hipLaunchKernelGGL(filter_k, dim3(1024), dim3(256), 0, stream, xh, nrm, tau, cnt_pb, buf2);
    hipLaunchKernelGGL(rerank_k, dim3(4096), dim3(256), 0, stream, x, cnt_pb, buf2, out);
}

// Round 8
// 237.248 us; speedup vs baseline: 1.8411x; 1.8411x over previous
//
#include <hip/hip_runtime.h>
#include <stdint.h>

// KNN K=16 over x (B=2, N=8192, D=64) f32. Output int32 (2,B,N,K): nn_idx, center_idx.
// Pipeline: split_k (bf16 hi + residual norms) -> red_k (batch maxima) -> tau_p
// (MFMA hi-only min-ladders over a 4096-sample, register-double-buffered
// streaming) -> tau_m (merge -> per-query threshold with PROVABLE Cauchy-Schwarz
// slop) -> filter_k (MFMA hi-only distance, BARRIER-FREE, register-double-
// buffered B-fragment pipeline, accepts via LDS atomics) -> rerank_k (exact f64).
// R7 LESSON: prefetch + full `#pragma unroll` on the 16-chunk loop let LLVM
// hoist ALL 15 prefetch sets (~270 VGPR demand under a 128 cap) -> wholesale
// scratch spill (WRITE_SIZE 425 MB vs 8 MB legit; tau_p 13x slower). The chunk
// loops are now PINNED ROLLED with `#pragma unroll 1` so exactly one prefetch
// buffer is live across an iteration boundary. Do NOT re-add unroll pragmas.
// Bound: |key_approx - key_true| <= 2(n_q E + e_q H) with e_i MEASURED in split_k,
// E = max e, H = Nmax + E. tau = u16_approx + 2*slop provably keeps all true
// top-16 (pigeonhole: u16 = 16th smallest of 128 column-minima over the
// 4096-sample >= sample-d16 >= population-d16).
constexpr int N_    = 8192;
constexpr int D_    = 64;
constexpr int K_    = 16;
constexpr int NQ    = 16384;          // 2*8192
constexpr int MS    = 8;              // m-superblocks per batch (1024 m each)
constexpr int CAPB  = 40;             // survivor cap per (query, superblock)

typedef __attribute__((ext_vector_type(8))) short bf16x8;
typedef __attribute__((ext_vector_type(4))) float f32x4;

template<int JN>
__device__ __forceinline__ void topk_insertf(float (&key)[JN], float nk) {
    if (nk < key[JN - 1]) {
        bool c[JN];
#pragma unroll
        for (int j = 0; j < JN; ++j) c[j] = nk < key[j];
#pragma unroll
        for (int j = JN - 1; j >= 1; --j)
            key[j] = c[j - 1] ? key[j - 1] : (c[j] ? nk : key[j]);
        key[0] = c[0] ? nk : key[0];
    }
}

__device__ __forceinline__ unsigned short bf16_rne(float f) {
    uint32_t u = __float_as_uint(f);
    return (unsigned short)((u + 0x7FFFu + ((u >> 16) & 1u)) >> 16);   // no NaN in data
}

// K1: bf16 hi split + true squared norms + residual norms. 16 lanes/row. grid=1024.
__global__ void __launch_bounds__(256) split_k(const float* __restrict__ x,
                                               unsigned short* __restrict__ xh,
                                               float* __restrict__ nrm,
                                               float* __restrict__ eres) {
    const int t = blockIdx.x * 256 + (int)threadIdx.x;    // one float4 per thread
    const int row = t >> 4, seg = t & 15;
    const float4 v = reinterpret_cast<const float4*>(x)[t];
    float f[4] = {v.x, v.y, v.z, v.w};
    unsigned short h[4];
    float sq = 0.f, esq = 0.f;
#pragma unroll
    for (int j = 0; j < 4; ++j) {
        sq = fmaf(f[j], f[j], sq);
        h[j] = bf16_rne(f[j]);
        float hf = __uint_as_float((uint32_t)h[j] << 16);
        float r  = f[j] - hf;
        esq = fmaf(r, r, esq);
    }
    sq  += __shfl_xor(sq, 1, 16);  sq  += __shfl_xor(sq, 2, 16);
    sq  += __shfl_xor(sq, 4, 16);  sq  += __shfl_xor(sq, 8, 16);
    esq += __shfl_xor(esq, 1, 16); esq += __shfl_xor(esq, 2, 16);
    esq += __shfl_xor(esq, 4, 16); esq += __shfl_xor(esq, 8, 16);
    if (seg == 0) { nrm[row] = sq; eres[row] = sqrtf(esq); }
    ushort4 hv = {h[0], h[1], h[2], h[3]};
    reinterpret_cast<ushort4*>(xh)[t] = hv;
}

// K1b: per-batch maxima: EH[b] = {Nmax, Emax} (inflated for f32 rounding). grid=2.
__global__ void __launch_bounds__(256) red_k(const float* __restrict__ nrm,
                                             const float* __restrict__ eres,
                                             float* __restrict__ EH) {
    __shared__ float mbuf[8];
    const int b = (int)blockIdx.x, tid = (int)threadIdx.x;
    float mn = 0.f, me = 0.f;
    for (int i = tid; i < N_; i += 256) {
        mn = fmaxf(mn, nrm[b * N_ + i]);
        me = fmaxf(me, eres[b * N_ + i]);
    }
#pragma unroll
    for (int s = 1; s < 64; s <<= 1) {
        mn = fmaxf(mn, __shfl_xor(mn, s, 64));
        me = fmaxf(me, __shfl_xor(me, s, 64));
    }
    const int w = tid >> 6;
    if ((tid & 63) == 0) { mbuf[w * 2] = mn; mbuf[w * 2 + 1] = me; }
    __syncthreads();
    if (tid == 0) {
        for (int i = 1; i < 4; ++i) {
            mn = fmaxf(mn, mbuf[i * 2]); me = fmaxf(me, mbuf[i * 2 + 1]);
        }
        EH[b * 2]     = sqrtf(mn) * 1.0002f + 1e-6f;      // Nmax upper bound
        EH[b * 2 + 1] = me * 1.0002f + 1e-7f;             // Emax upper bound
    }
}

// K2a: MFMA tau partials over a 4096-sample, register-double-buffered streaming.
// Block = 128q x 1024 samples (quarter sh), 16 chunks of 64. Next chunk's B
// frags + norms prefetched into regs during current chunk's MFMA/epilogue.
// Chunk loop PINNED ROLLED (unroll 1) -> exactly 1 prefetch buffer live.
// grid = 128 q-tiles x 4 quarters = 512.
__global__ void __launch_bounds__(256, 4) tau_p(const unsigned short* __restrict__ xh,
                                                const float* __restrict__ nrm,
                                                float* __restrict__ part) {
    __shared__ alignas(16) float nrmS[1024];                // 4 KB sample norms
    const int tid = (int)threadIdx.x;
    const int bid = (int)blockIdx.x;
    const int qt  = bid >> 2, sh = bid & 3;
    const int q0g = qt * 128;
    const int b   = q0g >> 13;                              // uniform (128 | 8192)
    const int q0l = q0g & (N_ - 1);
    const int s0  = sh * 1024;
    const unsigned short* __restrict__ xhb = xh + (size_t)b * N_ * D_;
    const float* __restrict__ nb = nrm + b * N_;
    const int w = tid >> 6, lane = tid & 63;
    const int wq = w >> 1, wm = w & 1;                      // 64q x 32s wave subtile
    const int l15 = lane & 15, quad = lane >> 4;

    *(float4*)(nrmS + tid * 4) = *(const float4*)(nb + s0 + tid * 4);

    bf16x8 Af[2][4];                                        // A frags from global
#pragma unroll
    for (int half = 0; half < 2; ++half) {
        const int eo = (half * 4 + quad) * 8;               // element offset in row
#pragma unroll
        for (int tm = 0; tm < 4; ++tm)
            Af[half][tm] = *(const bf16x8*)(xhb + (size_t)(q0l + wq * 64 + tm * 16 + l15) * D_ + eo);
    }
    bf16x8 Bf[2][2];                                        // chunk-0 B frags (pre-barrier)
#pragma unroll
    for (int half = 0; half < 2; ++half) {
        const int eo = (half * 4 + quad) * 8;
#pragma unroll
        for (int tn = 0; tn < 2; ++tn)
            Bf[half][tn] = *(const bf16x8*)(xhb + (size_t)(s0 + wm * 32 + tn * 16 + l15) * D_ + eo);
    }
    float lad[16];
#pragma unroll
    for (int j = 0; j < 16; ++j) lad[j] = __builtin_inff();
    __syncthreads();                                        // nrmS visible

    float nm0 = nrmS[wm * 32 + l15];
    float nm1 = nrmS[wm * 32 + 16 + l15];
#pragma unroll 1
    for (int mc = 0; mc < 16; ++mc) {
        bf16x8 Bn[2][2];                                    // prefetch next chunk
        float nn0 = 0.f, nn1 = 0.f;
        if (mc < 15) {
            const unsigned short* Bb = xhb + (size_t)(s0 + (mc + 1) * 64) * D_;
#pragma unroll
            for (int half = 0; half < 2; ++half) {
                const int eo = (half * 4 + quad) * 8;
#pragma unroll
                for (int tn = 0; tn < 2; ++tn)
                    Bn[half][tn] = *(const bf16x8*)(Bb + (size_t)(wm * 32 + tn * 16 + l15) * D_ + eo);
            }
            nn0 = nrmS[(mc + 1) * 64 + wm * 32 + l15];
            nn1 = nrmS[(mc + 1) * 64 + wm * 32 + 16 + l15];
        }
        f32x4 acc[4][2] = {};
#pragma unroll
        for (int half = 0; half < 2; ++half)
#pragma unroll
            for (int tm = 0; tm < 4; ++tm)
#pragma unroll
                for (int tn = 0; tn < 2; ++tn)
                    acc[tm][tn] = __builtin_amdgcn_mfma_f32_16x16x32_bf16(Af[half][tm], Bf[half][tn], acc[tm][tn], 0, 0, 0);
        // epilogue: C/D col=lane&15 (sample), row=quad*4+reg (q); depth-1 min
#pragma unroll
        for (int tn = 0; tn < 2; ++tn) {
            const float nm = tn ? nm1 : nm0;
#pragma unroll
            for (int tm = 0; tm < 4; ++tm)
#pragma unroll
                for (int reg = 0; reg < 4; ++reg)
                    lad[tm * 4 + reg] = fminf(lad[tm * 4 + reg],
                                              fmaf(-2.f, acc[tm][tn][reg], nm));
        }
        if (mc < 15) {
#pragma unroll
            for (int half = 0; half < 2; ++half)
#pragma unroll
                for (int tn = 0; tn < 2; ++tn) Bf[half][tn] = Bn[half][tn];
            nm0 = nn0; nm1 = nn1;
        }
    }
    // part[q][128]: offset = sh*32 + wm*16 + l15
#pragma unroll
    for (int tm = 0; tm < 4; ++tm)
#pragma unroll
        for (int reg = 0; reg < 4; ++reg) {
            const int q = q0g + wq * 64 + tm * 16 + quad * 4 + reg;
            part[(size_t)q * 128 + sh * 32 + wm * 16 + l15] = lad[tm * 4 + reg];
        }
}

// K2b: merge 128 partials/query -> tau with provable slop. grid = NQ/64 = 256.
__global__ void __launch_bounds__(64) tau_m(const float* __restrict__ part,
                                            const float* __restrict__ nrm,
                                            const float* __restrict__ eres,
                                            const float* __restrict__ EH,
                                            float* __restrict__ tau) {
    const int q = blockIdx.x * 64 + (int)threadIdx.x;
    const int b = q >> 13;
    const float4* p = reinterpret_cast<const float4*>(part + (size_t)q * 128);
    float key[K_];
#pragma unroll
    for (int j = 0; j < K_; ++j) key[j] = __builtin_inff();
    for (int i = 0; i < 32; ++i) {
        float4 v = p[i];
        topk_insertf<K_>(key, v.x); topk_insertf<K_>(key, v.y);
        topk_insertf<K_>(key, v.z); topk_insertf<K_>(key, v.w);
    }
    const float Nmax = EH[b * 2], Emax = EH[b * 2 + 1];
    const float H = Nmax + Emax;                            // >= max ||xh_m||
    const float nq = sqrtf(nrm[q]) * 1.0001f, eq = eres[q];
    tau[q] = key[15] + 4.f * (nq * Emax + eq * H) + 6e-3f;  // 2*s_q + f32 fudge
}

// K3: MFMA filter, BARRIER-FREE, register-double-buffered. Block = 128q x 1024m,
// 16 chunks of 64m; next chunk's B frags (4x16B) + 2 norms prefetched into regs
// before current chunk's MFMA/epilogue -> L2 latency overlaps compute. Chunk
// loop PINNED ROLLED (unroll 1). Accepts -> LDS lists. grid = 2*64*8 = 1024.
__global__ void __launch_bounds__(256, 4) filter_k(const unsigned short* __restrict__ xh,
                                                   const float* __restrict__ nrm,
                                                   const float* __restrict__ tau,
                                                   unsigned short* __restrict__ cnt_pb,
                                                   unsigned short* __restrict__ buf2) {
    __shared__ alignas(16) float nrmS[1024];                // 4 KB superblock norms
    __shared__ unsigned short lists[128 * CAPB];            // 10 KB
    __shared__ unsigned int cntL[128];
    const int tid = (int)threadIdx.x;
    const int bid = (int)blockIdx.x;
    const int b  = bid >> 9;
    const int qt = (bid >> 3) & 63;
    const int ms = bid & 7;
    const int q0 = qt * 128;
    const unsigned short* __restrict__ xhb = xh + (size_t)b * N_ * D_;
    const float* __restrict__ nb = nrm + b * N_;
    const int w = tid >> 6, lane = tid & 63;
    const int wq = w >> 1, wm = w & 1;                      // 64q x 32m wave subtile
    const int l15 = lane & 15, quad = lane >> 4;

    *(float4*)(nrmS + tid * 4) = *(const float4*)(nb + ms * 1024 + tid * 4);
    if (tid < 128) cntL[tid] = 0;

    bf16x8 Af[2][4];                                        // A frags from global
#pragma unroll
    for (int half = 0; half < 2; ++half) {
        const int eo = (half * 4 + quad) * 8;
#pragma unroll
        for (int tm = 0; tm < 4; ++tm)
            Af[half][tm] = *(const bf16x8*)(xhb + (size_t)(q0 + wq * 64 + tm * 16 + l15) * D_ + eo);
    }
    bf16x8 Bf[2][2];                                        // chunk-0 B frags (pre-barrier)
#pragma unroll
    for (int half = 0; half < 2; ++half) {
        const int eo = (half * 4 + quad) * 8;
#pragma unroll
        for (int tn = 0; tn < 2; ++tn)
            Bf[half][tn] = *(const bf16x8*)(xhb + (size_t)(ms * 1024 + wm * 32 + tn * 16 + l15) * D_ + eo);
    }
    f32x4 t4v[4];
#pragma unroll
    for (int tm = 0; tm < 4; ++tm)
        t4v[tm] = *(const f32x4*)(tau + (b << 13) + q0 + wq * 64 + tm * 16 + quad * 4);
    __syncthreads();                                        // nrmS visible

    float nm0 = nrmS[wm * 32 + l15];
    float nm1 = nrmS[wm * 32 + 16 + l15];
#pragma unroll 1
    for (int mc = 0; mc < 16; ++mc) {
        bf16x8 Bn[2][2];                                    // prefetch next chunk
        float nn0 = 0.f, nn1 = 0.f;
        if (mc < 15) {
            const unsigned short* Bb = xhb + (size_t)(ms * 1024 + (mc + 1) * 64) * D_;
#pragma unroll
            for (int half = 0; half < 2; ++half) {
                const int eo = (half * 4 + quad) * 8;
#pragma unroll
                for (int tn = 0; tn < 2; ++tn)
                    Bn[half][tn] = *(const bf16x8*)(Bb + (size_t)(wm * 32 + tn * 16 + l15) * D_ + eo);
            }
            nn0 = nrmS[(mc + 1) * 64 + wm * 32 + l15];
            nn1 = nrmS[(mc + 1) * 64 + wm * 32 + 16 + l15];
        }
        f32x4 acc[4][2] = {};
#pragma unroll
        for (int half = 0; half < 2; ++half)
#pragma unroll
            for (int tm = 0; tm < 4; ++tm)
#pragma unroll
                for (int tn = 0; tn < 2; ++tn)
                    acc[tm][tn] = __builtin_amdgcn_mfma_f32_16x16x32_bf16(Af[half][tm], Bf[half][tn], acc[tm][tn], 0, 0, 0);
        // epilogue: C/D col=lane&15 (m), row=quad*4+reg (q); accept key <= tau
#pragma unroll
        for (int tn = 0; tn < 2; ++tn) {
            const int mloc = mc * 64 + wm * 32 + tn * 16 + l15;
            const float nm = tn ? nm1 : nm0;
            const unsigned short mid = (unsigned short)(ms * 1024 + mloc);
#pragma unroll
            for (int tm = 0; tm < 4; ++tm)
#pragma unroll
                for (int reg = 0; reg < 4; ++reg) {
                    float keyf = fmaf(-2.f, acc[tm][tn][reg], nm);
                    if (keyf <= t4v[tm][reg]) {             // rare (~0.4%)
                        int ql = wq * 64 + tm * 16 + quad * 4 + reg;
                        unsigned pos = atomicAdd(&cntL[ql], 1u);    // LDS atomic
                        if (pos < CAPB) lists[ql * CAPB + pos] = mid;
                    }
                }
        }
        if (mc < 15) {
#pragma unroll
            for (int half = 0; half < 2; ++half)
#pragma unroll
                for (int tn = 0; tn < 2; ++tn) Bf[half][tn] = Bn[half][tn];
            nm0 = nn0; nm1 = nn1;
        }
    }
    __syncthreads();                                        // all waves' accepts visible
    if (tid < 128) {                                        // flush to fixed slots
        const int q = (b << 13) + q0 + tid;
        unsigned cn = cntL[tid]; cn = cn < CAPB ? cn : CAPB;
        cnt_pb[(size_t)q * MS + ms] = (unsigned short)cn;
        unsigned short* dst = buf2 + ((size_t)q * MS + ms) * CAPB;
        for (unsigned i = 0; i < cn; ++i) dst[i] = lists[tid * CAPB + i];
    }
}

// K4: exact f64 rerank, wave-per-query (32-VGPR latency-lean form; occupancy is
// the binding constraint). With the 4096-sample tau, total <= 64 for ~all
// queries -> single gather+f64+bitonic round. block 256 = 4 waves; grid = 4096.
__global__ void __launch_bounds__(256) rerank_k(const float* __restrict__ x,
                                                const unsigned short* __restrict__ cnt_pb,
                                                const unsigned short* __restrict__ buf2,
                                                int* __restrict__ out) {
    __shared__ float Qs[4 * 64];                           // 1 KB query rows
    __shared__ unsigned short ids[4 * MS * CAPB];          // 2.5 KB compacted survivors
    const int tid = (int)threadIdx.x;
    const int w = tid >> 6, lane = tid & 63;
    const int q = blockIdx.x * 4 + w;
    const int b = q >> 13, n = q & (N_ - 1);
    const float* __restrict__ xb = x + (size_t)b * N_ * D_;
    Qs[w * 64 + lane] = xb[(size_t)n * D_ + lane];

    int off[MS + 1]; off[0] = 0;                           // all lanes compute same
#pragma unroll
    for (int ms = 0; ms < MS; ++ms) {
        int c = (int)cnt_pb[(size_t)q * MS + ms]; c = c < CAPB ? c : CAPB;
        off[ms + 1] = off[ms] + c;
    }
    const int total = off[MS];                             // >= 16 guaranteed (true top-16 pass)
    for (int idx = lane; idx < total; idx += 64) {         // compact ids into LDS
        int ms = 0;
#pragma unroll
        for (int t = 1; t < MS; ++t) ms += (idx >= off[t]) ? 1 : 0;
        ids[(w * MS) * CAPB + idx] = buf2[((size_t)q * MS + ms) * CAPB + (idx - off[ms])];
    }
    __syncthreads();

    unsigned long long v = ~0ull;
    int consumed = 0;
    bool first = true;
    while (first || consumed < total) {
        const int myIdx = first ? lane : consumed + lane - 16;
        const bool take = (first || lane >= 16) && myIdx < total;
        unsigned long long nk = ~0ull;
        if (take) {
            const int id = (int)ids[(w * MS) * CAPB + myIdx];
            const float* __restrict__ crow = xb + (size_t)id * D_;
            double a0 = 0.0, a1 = 0.0, a2 = 0.0, a3 = 0.0;
#pragma unroll
            for (int j = 0; j < 16; ++j) {
                const float4 c  = *(const float4*)(crow + j * 4);        // per-lane gather
                const float4 qv = *(const float4*)(Qs + w * 64 + j * 4); // uniform -> broadcast
                double d0 = (double)qv.x - (double)c.x; a0 = fma(d0, d0, a0);
                double d1 = (double)qv.y - (double)c.y; a1 = fma(d1, d1, a1);
                double d2 = (double)qv.z - (double)c.z; a2 = fma(d2, d2, a2);
                double d3 = (double)qv.w - (double)c.w; a3 = fma(d3, d3, a3);
            }
            double s = (a0 + a1) + (a2 + a3);
            // s >= 0 -> f64 bits order-preserving; low 13 mantissa bits carry the id
            // for exact (dist, id) lexicographic compare (ties -> lower id).
            nk = ((unsigned long long)__double_as_longlong(s) & ~0x1FFFull) | (unsigned)id;
        }
        if (first || lane >= 16) v = nk;                   // lanes 0-15 keep running top-16
        // 64-lane bitonic sort ascending (21 steps)
#pragma unroll
        for (int k = 2; k <= 64; k <<= 1)
#pragma unroll
            for (int j = k >> 1; j > 0; j >>= 1) {
                unsigned long long o = __shfl_xor(v, j, 64);
                const bool keepmin = (((lane & k) == 0) == ((lane & j) == 0));
                unsigned long long mn = v < o ? v : o;
                unsigned long long mx = v < o ? o : v;
                v = keepmin ? mn : mx;
            }
        consumed += first ? 64 : 48;
        first = false;
    }
    if (lane < K_) {
        out[(size_t)q * K_ + lane]                   = (int)(v & 0x1FFFull);  // nn_idx
        out[(size_t)NQ * K_ + (size_t)q * K_ + lane] = n;                     // center_idx
    }
}

extern "C" void kernel_launch(void* const* d_in, const int* in_sizes, int n_in,
                              void* d_out, int out_size, void* d_ws, size_t ws_size,
                              hipStream_t stream) {
    const float* x = (const float*)d_in[0];
    int* out = (int*)d_out;
    char* ws = (char*)d_ws;
    float*          nrm    = (float*)ws;                          //  64 KB @ 0
    float*          tau    = (float*)(ws + (64 << 10));           //  64 KB
    float*          eres   = (float*)(ws + (128 << 10));          //  64 KB
    float*          EH     = (float*)(ws + (192 << 10));          //  16 B
    unsigned short* cnt_pb = (unsigned short*)(ws + (256 << 10)); // 256 KB
    unsigned short* xh     = (unsigned short*)(ws + (1 << 20));   //   2 MB
    unsigned short* buf2   = (unsigned short*)(ws + (5 << 20));   // 10.5 MB (16384*8*40*2)
    float*          part   = (float*)(ws + (5 << 20));            //   8 MB, ALIASES buf2:
    // part is written by tau_p and fully consumed by tau_m BEFORE filter_k writes buf2.

    hipLaunchKernelGGL(split_k,  dim3(1024), dim3(256), 0, stream, x, xh, nrm, eres);
    hipLaunchKernelGGL(red_k,    dim3(2),    dim3(256), 0, stream, nrm, eres, EH);
    hipLaunchKernelGGL(tau_p,    dim3(512),  dim3(256), 0, stream, xh, nrm, part);
    hipLaunchKernelGGL(tau_m,    dim3(256),  dim3(64),  0, stream, part, nrm, eres, EH, tau);
    hipLaunchKernelGGL(filter_k, dim3(1024), dim3(256), 0, stream, xh, nrm, tau, cnt_pb, buf2);
    hipLaunchKernelGGL(rerank_k, dim3(4096), dim3(256), 0, stream, x, cnt_pb, buf2, out);
}

// Round 9
// 222.092 us; speedup vs baseline: 1.9668x; 1.0682x over previous
//
#include <hip/hip_runtime.h>
#include <stdint.h>

// KNN K=16 over x (B=2, N=8192, D=64) f32. Output int32 (2,B,N,K): nn_idx, center_idx.
// Pipeline: split_k (bf16 hi + residual norms) -> red_k (batch maxima) -> tau_p
// (MFMA hi-only min-ladders over a 4096-sample) -> tau_m (merge -> per-query
// threshold with PROVABLE Cauchy-Schwarz slop) -> filter_k (MFMA hi-only
// distance, BARRIER-FREE, 64q x 1024m blocks for 8 blocks/CU occupancy,
// accepts via LDS atomics) -> rerank_k (exact f64, single round ~always).
// R7/R8 LESSON: register prefetch does NOT fit filter_k's budget — full unroll
// demanded ~270 VGPR (425 MB spill), rolled still spilled ~5 dwords/iter
// (87 MB). DO NOT re-add prefetch. R6 evidence: VGPR=64, occ 34.8% -> the
// kernel was GRID-limited (1024 blocks = 4/CU). This version doubles TLP:
// q-tile 128->64, grid 2048 = 8 blocks/CU, halved fragments (~58 data VGPR)
// under __launch_bounds__(256,8) so 8 waves/SIMD fit. CAPB semantics unchanged.
// Bound: |key_approx - key_true| <= 2(n_q E + e_q H) with e_i MEASURED in split_k,
// E = max e, H = Nmax + E. tau = u16_approx + 2*slop provably keeps all true
// top-16 (pigeonhole: u16 = 16th smallest of 128 column-minima over the
// 4096-sample >= sample-d16 >= population-d16).
constexpr int N_    = 8192;
constexpr int D_    = 64;
constexpr int K_    = 16;
constexpr int NQ    = 16384;          // 2*8192
constexpr int MS    = 8;              // m-superblocks per batch (1024 m each)
constexpr int CAPB  = 40;             // survivor cap per (query, superblock)

typedef __attribute__((ext_vector_type(8))) short bf16x8;
typedef __attribute__((ext_vector_type(4))) float f32x4;

template<int JN>
__device__ __forceinline__ void topk_insertf(float (&key)[JN], float nk) {
    if (nk < key[JN - 1]) {
        bool c[JN];
#pragma unroll
        for (int j = 0; j < JN; ++j) c[j] = nk < key[j];
#pragma unroll
        for (int j = JN - 1; j >= 1; --j)
            key[j] = c[j - 1] ? key[j - 1] : (c[j] ? nk : key[j]);
        key[0] = c[0] ? nk : key[0];
    }
}

__device__ __forceinline__ unsigned short bf16_rne(float f) {
    uint32_t u = __float_as_uint(f);
    return (unsigned short)((u + 0x7FFFu + ((u >> 16) & 1u)) >> 16);   // no NaN in data
}

// K1: bf16 hi split + true squared norms + residual norms. 16 lanes/row. grid=1024.
__global__ void __launch_bounds__(256) split_k(const float* __restrict__ x,
                                               unsigned short* __restrict__ xh,
                                               float* __restrict__ nrm,
                                               float* __restrict__ eres) {
    const int t = blockIdx.x * 256 + (int)threadIdx.x;    // one float4 per thread
    const int row = t >> 4, seg = t & 15;
    const float4 v = reinterpret_cast<const float4*>(x)[t];
    float f[4] = {v.x, v.y, v.z, v.w};
    unsigned short h[4];
    float sq = 0.f, esq = 0.f;
#pragma unroll
    for (int j = 0; j < 4; ++j) {
        sq = fmaf(f[j], f[j], sq);
        h[j] = bf16_rne(f[j]);
        float hf = __uint_as_float((uint32_t)h[j] << 16);
        float r  = f[j] - hf;
        esq = fmaf(r, r, esq);
    }
    sq  += __shfl_xor(sq, 1, 16);  sq  += __shfl_xor(sq, 2, 16);
    sq  += __shfl_xor(sq, 4, 16);  sq  += __shfl_xor(sq, 8, 16);
    esq += __shfl_xor(esq, 1, 16); esq += __shfl_xor(esq, 2, 16);
    esq += __shfl_xor(esq, 4, 16); esq += __shfl_xor(esq, 8, 16);
    if (seg == 0) { nrm[row] = sq; eres[row] = sqrtf(esq); }
    ushort4 hv = {h[0], h[1], h[2], h[3]};
    reinterpret_cast<ushort4*>(xh)[t] = hv;
}

// K1b: per-batch maxima: EH[b] = {Nmax, Emax} (inflated for f32 rounding). grid=2.
__global__ void __launch_bounds__(256) red_k(const float* __restrict__ nrm,
                                             const float* __restrict__ eres,
                                             float* __restrict__ EH) {
    __shared__ float mbuf[8];
    const int b = (int)blockIdx.x, tid = (int)threadIdx.x;
    float mn = 0.f, me = 0.f;
    for (int i = tid; i < N_; i += 256) {
        mn = fmaxf(mn, nrm[b * N_ + i]);
        me = fmaxf(me, eres[b * N_ + i]);
    }
#pragma unroll
    for (int s = 1; s < 64; s <<= 1) {
        mn = fmaxf(mn, __shfl_xor(mn, s, 64));
        me = fmaxf(me, __shfl_xor(me, s, 64));
    }
    const int w = tid >> 6;
    if ((tid & 63) == 0) { mbuf[w * 2] = mn; mbuf[w * 2 + 1] = me; }
    __syncthreads();
    if (tid == 0) {
        for (int i = 1; i < 4; ++i) {
            mn = fmaxf(mn, mbuf[i * 2]); me = fmaxf(me, mbuf[i * 2 + 1]);
        }
        EH[b * 2]     = sqrtf(mn) * 1.0002f + 1e-6f;      // Nmax upper bound
        EH[b * 2 + 1] = me * 1.0002f + 1e-7f;             // Emax upper bound
    }
}

// K2a: MFMA tau partials over a 4096-sample (R6-proven form, NO prefetch).
// Block = 128q x 1024 samples (quarter sh), 16 chunks of 64.
// grid = 128 q-tiles x 4 quarters = 512.
__global__ void __launch_bounds__(256, 4) tau_p(const unsigned short* __restrict__ xh,
                                                const float* __restrict__ nrm,
                                                float* __restrict__ part) {
    __shared__ alignas(16) float nrmS[1024];                // 4 KB sample norms
    const int tid = (int)threadIdx.x;
    const int bid = (int)blockIdx.x;
    const int qt  = bid >> 2, sh = bid & 3;
    const int q0g = qt * 128;
    const int b   = q0g >> 13;                              // uniform (128 | 8192)
    const int q0l = q0g & (N_ - 1);
    const int s0  = sh * 1024;
    const unsigned short* __restrict__ xhb = xh + (size_t)b * N_ * D_;
    const float* __restrict__ nb = nrm + b * N_;
    const int w = tid >> 6, lane = tid & 63;
    const int wq = w >> 1, wm = w & 1;                      // 64q x 32s wave subtile
    const int l15 = lane & 15, quad = lane >> 4;

    *(float4*)(nrmS + tid * 4) = *(const float4*)(nb + s0 + tid * 4);

    bf16x8 Af[2][4];                                        // A frags from global
#pragma unroll
    for (int half = 0; half < 2; ++half) {
        const int eo = (half * 4 + quad) * 8;               // element offset in row
#pragma unroll
        for (int tm = 0; tm < 4; ++tm)
            Af[half][tm] = *(const bf16x8*)(xhb + (size_t)(q0l + wq * 64 + tm * 16 + l15) * D_ + eo);
    }
    float lad[16];
#pragma unroll
    for (int j = 0; j < 16; ++j) lad[j] = __builtin_inff();
    __syncthreads();                                        // nrmS visible

    for (int mc = 0; mc < 16; ++mc) {
        const unsigned short* Bbase = xhb + (size_t)(s0 + mc * 64) * D_;
        bf16x8 Bf[2][2];                                    // B frags from global (coalesced lines)
#pragma unroll
        for (int half = 0; half < 2; ++half) {
            const int eo = (half * 4 + quad) * 8;
#pragma unroll
            for (int tn = 0; tn < 2; ++tn)
                Bf[half][tn] = *(const bf16x8*)(Bbase + (size_t)(wm * 32 + tn * 16 + l15) * D_ + eo);
        }
        f32x4 acc[4][2] = {};
#pragma unroll
        for (int half = 0; half < 2; ++half)
#pragma unroll
            for (int tm = 0; tm < 4; ++tm)
#pragma unroll
                for (int tn = 0; tn < 2; ++tn)
                    acc[tm][tn] = __builtin_amdgcn_mfma_f32_16x16x32_bf16(Af[half][tm], Bf[half][tn], acc[tm][tn], 0, 0, 0);
        // epilogue: C/D col=lane&15 (sample), row=quad*4+reg (q); depth-1 min
#pragma unroll
        for (int tn = 0; tn < 2; ++tn) {
            const float nm = nrmS[mc * 64 + wm * 32 + tn * 16 + l15];
#pragma unroll
            for (int tm = 0; tm < 4; ++tm)
#pragma unroll
                for (int reg = 0; reg < 4; ++reg)
                    lad[tm * 4 + reg] = fminf(lad[tm * 4 + reg],
                                              fmaf(-2.f, acc[tm][tn][reg], nm));
        }
    }
    // part[q][128]: offset = sh*32 + wm*16 + l15
#pragma unroll
    for (int tm = 0; tm < 4; ++tm)
#pragma unroll
        for (int reg = 0; reg < 4; ++reg) {
            const int q = q0g + wq * 64 + tm * 16 + quad * 4 + reg;
            part[(size_t)q * 128 + sh * 32 + wm * 16 + l15] = lad[tm * 4 + reg];
        }
}

// K2b: merge 128 partials/query -> tau with provable slop. grid = NQ/64 = 256.
__global__ void __launch_bounds__(64) tau_m(const float* __restrict__ part,
                                            const float* __restrict__ nrm,
                                            const float* __restrict__ eres,
                                            const float* __restrict__ EH,
                                            float* __restrict__ tau) {
    const int q = blockIdx.x * 64 + (int)threadIdx.x;
    const int b = q >> 13;
    const float4* p = reinterpret_cast<const float4*>(part + (size_t)q * 128);
    float key[K_];
#pragma unroll
    for (int j = 0; j < K_; ++j) key[j] = __builtin_inff();
    for (int i = 0; i < 32; ++i) {
        float4 v = p[i];
        topk_insertf<K_>(key, v.x); topk_insertf<K_>(key, v.y);
        topk_insertf<K_>(key, v.z); topk_insertf<K_>(key, v.w);
    }
    const float Nmax = EH[b * 2], Emax = EH[b * 2 + 1];
    const float H = Nmax + Emax;                            // >= max ||xh_m||
    const float nq = sqrtf(nrm[q]) * 1.0001f, eq = eres[q];
    tau[q] = key[15] + 4.f * (nq * Emax + eq * H) + 6e-3f;  // 2*s_q + f32 fudge
}

// K3: MFMA filter, BARRIER-FREE, OCCUPANCY-OPTIMIZED. Block = 64q x 1024m,
// 16 chunks of 64m; per wave 32q x 32m (Af[2][2], acc[2][2] -> ~58 data VGPR,
// 8 waves/SIMD under __launch_bounds__(256,8)). grid = 2*128*8 = 2048 blocks
// = 8 blocks/CU (was 4). B rows L2-resident; accepts -> LDS lists (DS atomics).
__global__ void __launch_bounds__(256, 8) filter_k(const unsigned short* __restrict__ xh,
                                                   const float* __restrict__ nrm,
                                                   const float* __restrict__ tau,
                                                   unsigned short* __restrict__ cnt_pb,
                                                   unsigned short* __restrict__ buf2) {
    __shared__ alignas(16) float nrmS[1024];                // 4 KB superblock norms
    __shared__ unsigned short lists[64 * CAPB];             // 5 KB
    __shared__ unsigned int cntL[64];
    const int tid = (int)threadIdx.x;
    const int bid = (int)blockIdx.x;
    const int b  = bid >> 10;
    const int qt = (bid >> 3) & 127;
    const int ms = bid & 7;
    const int q0 = qt * 64;
    const unsigned short* __restrict__ xhb = xh + (size_t)b * N_ * D_;
    const float* __restrict__ nb = nrm + b * N_;
    const int w = tid >> 6, lane = tid & 63;
    const int wq = w >> 1, wm = w & 1;                      // 32q x 32m wave subtile
    const int l15 = lane & 15, quad = lane >> 4;

    *(float4*)(nrmS + tid * 4) = *(const float4*)(nb + ms * 1024 + tid * 4);
    if (tid < 64) cntL[tid] = 0;

    bf16x8 Af[2][2];                                        // A frags from global
#pragma unroll
    for (int half = 0; half < 2; ++half) {
        const int eo = (half * 4 + quad) * 8;
#pragma unroll
        for (int tm = 0; tm < 2; ++tm)
            Af[half][tm] = *(const bf16x8*)(xhb + (size_t)(q0 + wq * 32 + tm * 16 + l15) * D_ + eo);
    }
    f32x4 t4v[2];
#pragma unroll
    for (int tm = 0; tm < 2; ++tm)
        t4v[tm] = *(const f32x4*)(tau + (b << 13) + q0 + wq * 32 + tm * 16 + quad * 4);
    __syncthreads();                                        // nrmS visible

    for (int mc = 0; mc < 16; ++mc) {
        const unsigned short* Bbase = xhb + (size_t)(ms * 1024 + mc * 64) * D_;
        bf16x8 Bf[2][2];                                    // coalesced line gathers
#pragma unroll
        for (int half = 0; half < 2; ++half) {
            const int eo = (half * 4 + quad) * 8;
#pragma unroll
            for (int tn = 0; tn < 2; ++tn)
                Bf[half][tn] = *(const bf16x8*)(Bbase + (size_t)(wm * 32 + tn * 16 + l15) * D_ + eo);
        }
        f32x4 acc[2][2] = {};
#pragma unroll
        for (int half = 0; half < 2; ++half)
#pragma unroll
            for (int tm = 0; tm < 2; ++tm)
#pragma unroll
                for (int tn = 0; tn < 2; ++tn)
                    acc[tm][tn] = __builtin_amdgcn_mfma_f32_16x16x32_bf16(Af[half][tm], Bf[half][tn], acc[tm][tn], 0, 0, 0);
        // epilogue: C/D col=lane&15 (m), row=quad*4+reg (q); accept key <= tau
#pragma unroll
        for (int tn = 0; tn < 2; ++tn) {
            const int mloc = mc * 64 + wm * 32 + tn * 16 + l15;
            const float nm = nrmS[mloc];
            const unsigned short mid = (unsigned short)(ms * 1024 + mloc);
#pragma unroll
            for (int tm = 0; tm < 2; ++tm)
#pragma unroll
                for (int reg = 0; reg < 4; ++reg) {
                    float keyf = fmaf(-2.f, acc[tm][tn][reg], nm);
                    if (keyf <= t4v[tm][reg]) {             // rare (~0.4%)
                        int ql = wq * 32 + tm * 16 + quad * 4 + reg;
                        unsigned pos = atomicAdd(&cntL[ql], 1u);    // LDS atomic
                        if (pos < CAPB) lists[ql * CAPB + pos] = mid;
                    }
                }
        }
    }
    __syncthreads();                                        // all waves' accepts visible
    if (tid < 64) {                                         // flush to fixed slots
        const int q = (b << 13) + q0 + tid;
        unsigned cn = cntL[tid]; cn = cn < CAPB ? cn : CAPB;
        cnt_pb[(size_t)q * MS + ms] = (unsigned short)cn;
        unsigned short* dst = buf2 + ((size_t)q * MS + ms) * CAPB;
        for (unsigned i = 0; i < cn; ++i) dst[i] = lists[tid * CAPB + i];
    }
}

// K4: exact f64 rerank, wave-per-query (32-VGPR latency-lean form; occupancy is
// the binding constraint). With the 4096-sample tau, total <= 64 for ~all
// queries -> single gather+f64+bitonic round. block 256 = 4 waves; grid = 4096.
__global__ void __launch_bounds__(256) rerank_k(const float* __restrict__ x,
                                                const unsigned short* __restrict__ cnt_pb,
                                                const unsigned short* __restrict__ buf2,
                                                int* __restrict__ out) {
    __shared__ float Qs[4 * 64];                           // 1 KB query rows
    __shared__ unsigned short ids[4 * MS * CAPB];          // 2.5 KB compacted survivors
    const int tid = (int)threadIdx.x;
    const int w = tid >> 6, lane = tid & 63;
    const int q = blockIdx.x * 4 + w;
    const int b = q >> 13, n = q & (N_ - 1);
    const float* __restrict__ xb = x + (size_t)b * N_ * D_;
    Qs[w * 64 + lane] = xb[(size_t)n * D_ + lane];

    int off[MS + 1]; off[0] = 0;                           // all lanes compute same
#pragma unroll
    for (int ms = 0; ms < MS; ++ms) {
        int c = (int)cnt_pb[(size_t)q * MS + ms]; c = c < CAPB ? c : CAPB;
        off[ms + 1] = off[ms] + c;
    }
    const int total = off[MS];                             // >= 16 guaranteed (true top-16 pass)
    for (int idx = lane; idx < total; idx += 64) {         // compact ids into LDS
        int ms = 0;
#pragma unroll
        for (int t = 1; t < MS; ++t) ms += (idx >= off[t]) ? 1 : 0;
        ids[(w * MS) * CAPB + idx] = buf2[((size_t)q * MS + ms) * CAPB + (idx - off[ms])];
    }
    __syncthreads();

    unsigned long long v = ~0ull;
    int consumed = 0;
    bool first = true;
    while (first || consumed < total) {
        const int myIdx = first ? lane : consumed + lane - 16;
        const bool take = (first || lane >= 16) && myIdx < total;
        unsigned long long nk = ~0ull;
        if (take) {
            const int id = (int)ids[(w * MS) * CAPB + myIdx];
            const float* __restrict__ crow = xb + (size_t)id * D_;
            double a0 = 0.0, a1 = 0.0, a2 = 0.0, a3 = 0.0;
#pragma unroll
            for (int j = 0; j < 16; ++j) {
                const float4 c  = *(const float4*)(crow + j * 4);        // per-lane gather
                const float4 qv = *(const float4*)(Qs + w * 64 + j * 4); // uniform -> broadcast
                double d0 = (double)qv.x - (double)c.x; a0 = fma(d0, d0, a0);
                double d1 = (double)qv.y - (double)c.y; a1 = fma(d1, d1, a1);
                double d2 = (double)qv.z - (double)c.z; a2 = fma(d2, d2, a2);
                double d3 = (double)qv.w - (double)c.w; a3 = fma(d3, d3, a3);
            }
            double s = (a0 + a1) + (a2 + a3);
            // s >= 0 -> f64 bits order-preserving; low 13 mantissa bits carry the id
            // for exact (dist, id) lexicographic compare (ties -> lower id).
            nk = ((unsigned long long)__double_as_longlong(s) & ~0x1FFFull) | (unsigned)id;
        }
        if (first || lane >= 16) v = nk;                   // lanes 0-15 keep running top-16
        // 64-lane bitonic sort ascending (21 steps)
#pragma unroll
        for (int k = 2; k <= 64; k <<= 1)
#pragma unroll
            for (int j = k >> 1; j > 0; j >>= 1) {
                unsigned long long o = __shfl_xor(v, j, 64);
                const bool keepmin = (((lane & k) == 0) == ((lane & j) == 0));
                unsigned long long mn = v < o ? v : o;
                unsigned long long mx = v < o ? o : v;
                v = keepmin ? mn : mx;
            }
        consumed += first ? 64 : 48;
        first = false;
    }
    if (lane < K_) {
        out[(size_t)q * K_ + lane]                   = (int)(v & 0x1FFFull);  // nn_idx
        out[(size_t)NQ * K_ + (size_t)q * K_ + lane] = n;                     // center_idx
    }
}

extern "C" void kernel_launch(void* const* d_in, const int* in_sizes, int n_in,
                              void* d_out, int out_size, void* d_ws, size_t ws_size,
                              hipStream_t stream) {
    const float* x = (const float*)d_in[0];
    int* out = (int*)d_out;
    char* ws = (char*)d_ws;
    float*          nrm    = (float*)ws;                          //  64 KB @ 0
    float*          tau    = (float*)(ws + (64 << 10));           //  64 KB
    float*          eres   = (float*)(ws + (128 << 10));          //  64 KB
    float*          EH     = (float*)(ws + (192 << 10));          //  16 B
    unsigned short* cnt_pb = (unsigned short*)(ws + (256 << 10)); // 256 KB
    unsigned short* xh     = (unsigned short*)(ws + (1 << 20));   //   2 MB
    unsigned short* buf2   = (unsigned short*)(ws + (5 << 20));   // 10.5 MB (16384*8*40*2)
    float*          part   = (float*)(ws + (5 << 20));            //   8 MB, ALIASES buf2:
    // part is written by tau_p and fully consumed by tau_m BEFORE filter_k writes buf2.

    hipLaunchKernelGGL(split_k,  dim3(1024), dim3(256), 0, stream, x, xh, nrm, eres);
    hipLaunchKernelGGL(red_k,    dim3(2),    dim3(256), 0, stream, nrm, eres, EH);
    hipLaunchKernelGGL(tau_p,    dim3(512),  dim3(256), 0, stream, xh, nrm, part);
    hipLaunchKernelGGL(tau_m,    dim3(256),  dim3(64),  0, stream, part, nrm, eres, EH, tau);
    hipLaunchKernelGGL(filter_k, dim3(2048), dim3(256), 0, stream, xh, nrm, tau, cnt_pb, buf2);
    hipLaunchKernelGGL(rerank_k, dim3(4096), dim3(256), 0, stream, x, cnt_pb, buf2, out);
}

// Round 11
// 198.103 us; speedup vs baseline: 2.2049x; 1.1211x over previous
//
#include <hip/hip_runtime.h>
#include <stdint.h>

// KNN K=16 over x (B=2, N=8192, D=64) f32. Output int32 (2,B,N,K): nn_idx, center_idx.
// Pipeline: split_k -> red_k -> tau_p (MFMA min-ladders over 4096-sample, LDS-staged
// B) -> tau_m -> filter_k (MFMA filter, LDS-staged B, accepts via LDS atomics)
// -> rerank_k (exact f64, single round ~always).
// LESSONS LOG:
//  R7: prefetch + full unroll -> ~270 VGPR demand -> 425 MB scratch spill. NO unroll.
//  R8: prefetch rolled still spilled ~5 dwords/iter (87 MB). NO reg prefetch.
//  R9: q-tile 64 + 8 blocks/CU: occupancy 2x but duration 2x — duration scales
//      with TOTAL B-gather line work (16 lines/instr, wm-redundant) -> the kernel
//      is VECTOR-MEMORY-THROUGHPUT bound, not latency bound. Fix = reduce gather
//      work: stage B chunks into LDS once per block (contiguous, no redundancy),
//      ds_read fragments with XOR swizzle (row&7)<<4 (2-way banks = free).
// Bound: |key_approx - key_true| <= 2(n_q E + e_q H), E = max e, H = Nmax + E.
// tau = u16 + 2*slop provably keeps all true top-16 (pigeonhole: u16 = 16th
// smallest of 128 column-minima over the 4096-sample >= sample-d16 >= pop-d16).
constexpr int N_    = 8192;
constexpr int D_    = 64;
constexpr int K_    = 16;
constexpr int NQ    = 16384;          // 2*8192
constexpr int MS    = 8;              // m-superblocks per batch (1024 m each)
constexpr int CAPB  = 40;             // survivor cap per (query, superblock)

typedef __attribute__((ext_vector_type(8))) short bf16x8;
typedef __attribute__((ext_vector_type(4))) float f32x4;

template<int JN>
__device__ __forceinline__ void topk_insertf(float (&key)[JN], float nk) {
    if (nk < key[JN - 1]) {
        bool c[JN];
#pragma unroll
        for (int j = 0; j < JN; ++j) c[j] = nk < key[j];
#pragma unroll
        for (int j = JN - 1; j >= 1; --j)
            key[j] = c[j - 1] ? key[j - 1] : (c[j] ? nk : key[j]);
        key[0] = c[0] ? nk : key[0];
    }
}

__device__ __forceinline__ unsigned short bf16_rne(float f) {
    uint32_t u = __float_as_uint(f);
    return (unsigned short)((u + 0x7FFFu + ((u >> 16) & 1u)) >> 16);   // no NaN in data
}

// Stage one 64-row x 64-col bf16 chunk (8 KB) global->LDS, XOR-swizzled rows.
// 256 threads x 2 x 16 B. Write banks: per-16-lane phase 2-way (free).
__device__ __forceinline__ void stage_chunk(const unsigned short* __restrict__ gsrc,
                                            unsigned short* __restrict__ lbuf,
                                            int tid) {
#pragma unroll
    for (int p = 0; p < 2; ++p) {
        const int idx = tid + p * 256;          // 16B slot 0..511
        const int row = idx >> 3;               // 0..63
        const int o16 = idx & 7;                // 16B unit within row
        bf16x8 t = *(const bf16x8*)(gsrc + (size_t)row * 64 + o16 * 8);
        const int dst = row * 128 + ((o16 * 16) ^ ((row & 7) << 4));
        *(bf16x8*)((char*)lbuf + dst) = t;
    }
}

// K1: bf16 hi split + true squared norms + residual norms. 16 lanes/row. grid=1024.
__global__ void __launch_bounds__(256) split_k(const float* __restrict__ x,
                                               unsigned short* __restrict__ xh,
                                               float* __restrict__ nrm,
                                               float* __restrict__ eres) {
    const int t = blockIdx.x * 256 + (int)threadIdx.x;    // one float4 per thread
    const int row = t >> 4, seg = t & 15;
    const float4 v = reinterpret_cast<const float4*>(x)[t];
    float f[4] = {v.x, v.y, v.z, v.w};
    unsigned short h[4];
    float sq = 0.f, esq = 0.f;
#pragma unroll
    for (int j = 0; j < 4; ++j) {
        sq = fmaf(f[j], f[j], sq);
        h[j] = bf16_rne(f[j]);
        float hf = __uint_as_float((uint32_t)h[j] << 16);
        float r  = f[j] - hf;
        esq = fmaf(r, r, esq);
    }
    sq  += __shfl_xor(sq, 1, 16);  sq  += __shfl_xor(sq, 2, 16);
    sq  += __shfl_xor(sq, 4, 16);  sq  += __shfl_xor(sq, 8, 16);
    esq += __shfl_xor(esq, 1, 16); esq += __shfl_xor(esq, 2, 16);
    esq += __shfl_xor(esq, 4, 16); esq += __shfl_xor(esq, 8, 16);
    if (seg == 0) { nrm[row] = sq; eres[row] = sqrtf(esq); }
    ushort4 hv = {h[0], h[1], h[2], h[3]};
    reinterpret_cast<ushort4*>(xh)[t] = hv;
}

// K1b: per-batch maxima: EH[b] = {Nmax, Emax} (inflated for f32 rounding). grid=2.
__global__ void __launch_bounds__(256) red_k(const float* __restrict__ nrm,
                                             const float* __restrict__ eres,
                                             float* __restrict__ EH) {
    __shared__ float mbuf[8];
    const int b = (int)blockIdx.x, tid = (int)threadIdx.x;
    float mn = 0.f, me = 0.f;
    for (int i = tid; i < N_; i += 256) {
        mn = fmaxf(mn, nrm[b * N_ + i]);
        me = fmaxf(me, eres[b * N_ + i]);
    }
#pragma unroll
    for (int s = 1; s < 64; s <<= 1) {
        mn = fmaxf(mn, __shfl_xor(mn, s, 64));
        me = fmaxf(me, __shfl_xor(me, s, 64));
    }
    const int w = tid >> 6;
    if ((tid & 63) == 0) { mbuf[w * 2] = mn; mbuf[w * 2 + 1] = me; }
    __syncthreads();
    if (tid == 0) {
        for (int i = 1; i < 4; ++i) {
            mn = fmaxf(mn, mbuf[i * 2]); me = fmaxf(me, mbuf[i * 2 + 1]);
        }
        EH[b * 2]     = sqrtf(mn) * 1.0002f + 1e-6f;      // Nmax upper bound
        EH[b * 2 + 1] = me * 1.0002f + 1e-7f;             // Emax upper bound
    }
}

// K2a: MFMA tau partials over a 4096-sample, LDS-staged B (dbuf, 1 barrier/chunk).
// Block = 128q x 1024 samples (quarter sh), 16 chunks of 64.
// grid = 128 q-tiles x 4 quarters = 512 (2 blocks/CU -> bounds (256,2), no spill).
__global__ void __launch_bounds__(256, 2) tau_p(const unsigned short* __restrict__ xh,
                                                const float* __restrict__ nrm,
                                                float* __restrict__ part) {
    __shared__ alignas(16) float nrmS[1024];                // 4 KB sample norms
    __shared__ alignas(16) unsigned short Bs[2][64 * 64];   // 16 KB dbuf B chunks
    const int tid = (int)threadIdx.x;
    const int bid = (int)blockIdx.x;
    const int qt  = bid >> 2, sh = bid & 3;
    const int q0g = qt * 128;
    const int b   = q0g >> 13;                              // uniform (128 | 8192)
    const int q0l = q0g & (N_ - 1);
    const int s0  = sh * 1024;
    const unsigned short* __restrict__ xhb = xh + (size_t)b * N_ * D_;
    const float* __restrict__ nb = nrm + b * N_;
    const int w = tid >> 6, lane = tid & 63;
    const int wq = w >> 1, wm = w & 1;                      // 64q x 32s wave subtile
    const int l15 = lane & 15, quad = lane >> 4;
    const int swzL = (l15 & 7) << 4;                        // row-XOR for frag reads

    *(float4*)(nrmS + tid * 4) = *(const float4*)(nb + s0 + tid * 4);

    bf16x8 Af[2][4];                                        // A frags from global
#pragma unroll
    for (int half = 0; half < 2; ++half) {
        const int eo = (half * 4 + quad) * 8;               // element offset in row
#pragma unroll
        for (int tm = 0; tm < 4; ++tm)
            Af[half][tm] = *(const bf16x8*)(xhb + (size_t)(q0l + wq * 64 + tm * 16 + l15) * D_ + eo);
    }
    float lad[16];
#pragma unroll
    for (int j = 0; j < 16; ++j) lad[j] = __builtin_inff();

    stage_chunk(xhb + (size_t)s0 * D_, Bs[0], tid);         // chunk 0
    __syncthreads();                                        // nrmS + chunk 0 visible

#pragma unroll 1
    for (int mc = 0; mc < 16; ++mc) {
        if (mc < 15)
            stage_chunk(xhb + (size_t)(s0 + (mc + 1) * 64) * D_, Bs[(mc + 1) & 1], tid);
        const char* Bc = (const char*)Bs[mc & 1];
        bf16x8 Bf[2][2];
#pragma unroll
        for (int half = 0; half < 2; ++half) {
            const int off = (half * 4 + quad) * 16;
#pragma unroll
            for (int tn = 0; tn < 2; ++tn) {
                const int r = wm * 32 + tn * 16 + l15;
                Bf[half][tn] = *(const bf16x8*)(Bc + r * 128 + (off ^ swzL));
            }
        }
        f32x4 acc[4][2] = {};
#pragma unroll
        for (int half = 0; half < 2; ++half)
#pragma unroll
            for (int tm = 0; tm < 4; ++tm)
#pragma unroll
                for (int tn = 0; tn < 2; ++tn)
                    acc[tm][tn] = __builtin_amdgcn_mfma_f32_16x16x32_bf16(Af[half][tm], Bf[half][tn], acc[tm][tn], 0, 0, 0);
        // epilogue: C/D col=lane&15 (sample), row=quad*4+reg (q); depth-1 min
#pragma unroll
        for (int tn = 0; tn < 2; ++tn) {
            const float nm = nrmS[mc * 64 + wm * 32 + tn * 16 + l15];
#pragma unroll
            for (int tm = 0; tm < 4; ++tm)
#pragma unroll
                for (int reg = 0; reg < 4; ++reg)
                    lad[tm * 4 + reg] = fminf(lad[tm * 4 + reg],
                                              fmaf(-2.f, acc[tm][tn][reg], nm));
        }
        __syncthreads();                                    // dbuf handoff
    }
    // part[q][128]: offset = sh*32 + wm*16 + l15
#pragma unroll
    for (int tm = 0; tm < 4; ++tm)
#pragma unroll
        for (int reg = 0; reg < 4; ++reg) {
            const int q = q0g + wq * 64 + tm * 16 + quad * 4 + reg;
            part[(size_t)q * 128 + sh * 32 + wm * 16 + l15] = lad[tm * 4 + reg];
        }
}

// K2b: merge 128 partials/query -> tau with provable slop. grid = NQ/64 = 256.
__global__ void __launch_bounds__(64) tau_m(const float* __restrict__ part,
                                            const float* __restrict__ nrm,
                                            const float* __restrict__ eres,
                                            const float* __restrict__ EH,
                                            float* __restrict__ tau) {
    const int q = blockIdx.x * 64 + (int)threadIdx.x;
    const int b = q >> 13;
    const float4* p = reinterpret_cast<const float4*>(part + (size_t)q * 128);
    float key[K_];
#pragma unroll
    for (int j = 0; j < K_; ++j) key[j] = __builtin_inff();
    for (int i = 0; i < 32; ++i) {
        float4 v = p[i];
        topk_insertf<K_>(key, v.x); topk_insertf<K_>(key, v.y);
        topk_insertf<K_>(key, v.z); topk_insertf<K_>(key, v.w);
    }
    const float Nmax = EH[b * 2], Emax = EH[b * 2 + 1];
    const float H = Nmax + Emax;                            // >= max ||xh_m||
    const float nq = sqrtf(nrm[q]) * 1.0001f, eq = eres[q];
    tau[q] = key[15] + 4.f * (nq * Emax + eq * H) + 6e-3f;  // 2*s_q + f32 fudge
}

// K3: MFMA filter, LDS-staged B (dbuf, 1 barrier/chunk). Block = 128q x 1024m
// (R6 geometry, grid 1024); 16 chunks of 64m. B chunk staged once per block
// (contiguous 8 KB, no gather redundancy) then ds_read with XOR swizzle.
// bounds (256,3): VGPR cap 170 -> the ~110-reg live set CANNOT spill; R6's
// measured occupancy was ~2.8 blocks/CU anyway. Accepts -> LDS lists.
__global__ void __launch_bounds__(256, 3) filter_k(const unsigned short* __restrict__ xh,
                                                   const float* __restrict__ nrm,
                                                   const float* __restrict__ tau,
                                                   unsigned short* __restrict__ cnt_pb,
                                                   unsigned short* __restrict__ buf2) {
    __shared__ alignas(16) float nrmS[1024];                // 4 KB superblock norms
    __shared__ alignas(16) unsigned short Bs[2][64 * 64];   // 16 KB dbuf B chunks
    __shared__ unsigned short lists[128 * CAPB];            // 10 KB
    __shared__ unsigned int cntL[128];
    const int tid = (int)threadIdx.x;
    const int bid = (int)blockIdx.x;
    const int b  = bid >> 9;
    const int qt = (bid >> 3) & 63;
    const int ms = bid & 7;
    const int q0 = qt * 128;
    const unsigned short* __restrict__ xhb = xh + (size_t)b * N_ * D_;
    const float* __restrict__ nb = nrm + b * N_;
    const int w = tid >> 6, lane = tid & 63;
    const int wq = w >> 1, wm = w & 1;                      // 64q x 32m wave subtile
    const int l15 = lane & 15, quad = lane >> 4;
    const int swzL = (l15 & 7) << 4;                        // row-XOR for frag reads

    *(float4*)(nrmS + tid * 4) = *(const float4*)(nb + ms * 1024 + tid * 4);
    if (tid < 128) cntL[tid] = 0;

    bf16x8 Af[2][4];                                        // A frags from global
#pragma unroll
    for (int half = 0; half < 2; ++half) {
        const int eo = (half * 4 + quad) * 8;
#pragma unroll
        for (int tm = 0; tm < 4; ++tm)
            Af[half][tm] = *(const bf16x8*)(xhb + (size_t)(q0 + wq * 64 + tm * 16 + l15) * D_ + eo);
    }
    f32x4 t4v[4];
#pragma unroll
    for (int tm = 0; tm < 4; ++tm)
        t4v[tm] = *(const f32x4*)(tau + (b << 13) + q0 + wq * 64 + tm * 16 + quad * 4);

    stage_chunk(xhb + (size_t)(ms * 1024) * D_, Bs[0], tid);  // chunk 0
    __syncthreads();                                        // nrmS + cntL + chunk 0 visible

#pragma unroll 1
    for (int mc = 0; mc < 16; ++mc) {
        if (mc < 15)
            stage_chunk(xhb + (size_t)(ms * 1024 + (mc + 1) * 64) * D_, Bs[(mc + 1) & 1], tid);
        const char* Bc = (const char*)Bs[mc & 1];
        bf16x8 Bf[2][2];
#pragma unroll
        for (int half = 0; half < 2; ++half) {
            const int off = (half * 4 + quad) * 16;
#pragma unroll
            for (int tn = 0; tn < 2; ++tn) {
                const int r = wm * 32 + tn * 16 + l15;
                Bf[half][tn] = *(const bf16x8*)(Bc + r * 128 + (off ^ swzL));
            }
        }
        f32x4 acc[4][2] = {};
#pragma unroll
        for (int half = 0; half < 2; ++half)
#pragma unroll
            for (int tm = 0; tm < 4; ++tm)
#pragma unroll
                for (int tn = 0; tn < 2; ++tn)
                    acc[tm][tn] = __builtin_amdgcn_mfma_f32_16x16x32_bf16(Af[half][tm], Bf[half][tn], acc[tm][tn], 0, 0, 0);
        // epilogue: C/D col=lane&15 (m), row=quad*4+reg (q); accept key <= tau
#pragma unroll
        for (int tn = 0; tn < 2; ++tn) {
            const int mloc = mc * 64 + wm * 32 + tn * 16 + l15;
            const float nm = nrmS[mloc];
            const unsigned short mid = (unsigned short)(ms * 1024 + mloc);
#pragma unroll
            for (int tm = 0; tm < 4; ++tm)
#pragma unroll
                for (int reg = 0; reg < 4; ++reg) {
                    float keyf = fmaf(-2.f, acc[tm][tn][reg], nm);
                    if (keyf <= t4v[tm][reg]) {             // rare (~0.4%)
                        int ql = wq * 64 + tm * 16 + quad * 4 + reg;
                        unsigned pos = atomicAdd(&cntL[ql], 1u);    // LDS atomic
                        if (pos < CAPB) lists[ql * CAPB + pos] = mid;
                    }
                }
        }
        __syncthreads();                                    // dbuf handoff
    }
    if (tid < 128) {                                        // flush to fixed slots
        const int q = (b << 13) + q0 + tid;
        unsigned cn = cntL[tid]; cn = cn < CAPB ? cn : CAPB;
        cnt_pb[(size_t)q * MS + ms] = (unsigned short)cn;
        unsigned short* dst = buf2 + ((size_t)q * MS + ms) * CAPB;
        for (unsigned i = 0; i < cn; ++i) dst[i] = lists[tid * CAPB + i];
    }
}

// K4: exact f64 rerank, wave-per-query (32-VGPR latency-lean form; occupancy is
// the binding constraint). With the 4096-sample tau, total <= 64 for ~all
// queries -> single gather+f64+bitonic round. block 256 = 4 waves; grid = 4096.
__global__ void __launch_bounds__(256) rerank_k(const float* __restrict__ x,
                                                const unsigned short* __restrict__ cnt_pb,
                                                const unsigned short* __restrict__ buf2,
                                                int* __restrict__ out) {
    __shared__ float Qs[4 * 64];                           // 1 KB query rows
    __shared__ unsigned short ids[4 * MS * CAPB];          // 2.5 KB compacted survivors
    const int tid = (int)threadIdx.x;
    const int w = tid >> 6, lane = tid & 63;
    const int q = blockIdx.x * 4 + w;
    const int b = q >> 13, n = q & (N_ - 1);
    const float* __restrict__ xb = x + (size_t)b * N_ * D_;
    Qs[w * 64 + lane] = xb[(size_t)n * D_ + lane];

    int off[MS + 1]; off[0] = 0;                           // all lanes compute same
#pragma unroll
    for (int ms = 0; ms < MS; ++ms) {
        int c = (int)cnt_pb[(size_t)q * MS + ms]; c = c < CAPB ? c : CAPB;
        off[ms + 1] = off[ms] + c;
    }
    const int total = off[MS];                             // >= 16 guaranteed (true top-16 pass)
    for (int idx = lane; idx < total; idx += 64) {         // compact ids into LDS
        int ms = 0;
#pragma unroll
        for (int t = 1; t < MS; ++t) ms += (idx >= off[t]) ? 1 : 0;
        ids[(w * MS) * CAPB + idx] = buf2[((size_t)q * MS + ms) * CAPB + (idx - off[ms])];
    }
    __syncthreads();

    unsigned long long v = ~0ull;
    int consumed = 0;
    bool first = true;
    while (first || consumed < total) {
        const int myIdx = first ? lane : consumed + lane - 16;
        const bool take = (first || lane >= 16) && myIdx < total;
        unsigned long long nk = ~0ull;
        if (take) {
            const int id = (int)ids[(w * MS) * CAPB + myIdx];
            const float* __restrict__ crow = xb + (size_t)id * D_;
            double a0 = 0.0, a1 = 0.0, a2 = 0.0, a3 = 0.0;
#pragma unroll
            for (int j = 0; j < 16; ++j) {
                const float4 c  = *(const float4*)(crow + j * 4);        // per-lane gather
                const float4 qv = *(const float4*)(Qs + w * 64 + j * 4); // uniform -> broadcast
                double d0 = (double)qv.x - (double)c.x; a0 = fma(d0, d0, a0);
                double d1 = (double)qv.y - (double)c.y; a1 = fma(d1, d1, a1);
                double d2 = (double)qv.z - (double)c.z; a2 = fma(d2, d2, a2);
                double d3 = (double)qv.w - (double)c.w; a3 = fma(d3, d3, a3);
            }
            double s = (a0 + a1) + (a2 + a3);
            // s >= 0 -> f64 bits order-preserving; low 13 mantissa bits carry the id
            // for exact (dist, id) lexicographic compare (ties -> lower id).
            nk = ((unsigned long long)__double_as_longlong(s) & ~0x1FFFull) | (unsigned)id;
        }
        if (first || lane >= 16) v = nk;                   // lanes 0-15 keep running top-16
        // 64-lane bitonic sort ascending (21 steps)
#pragma unroll
        for (int k = 2; k <= 64; k <<= 1)
#pragma unroll
            for (int j = k >> 1; j > 0; j >>= 1) {
                unsigned long long o = __shfl_xor(v, j, 64);
                const bool keepmin = (((lane & k) == 0) == ((lane & j) == 0));
                unsigned long long mn = v < o ? v : o;
                unsigned long long mx = v < o ? o : v;
                v = keepmin ? mn : mx;
            }
        consumed += first ? 64 : 48;
        first = false;
    }
    if (lane < K_) {
        out[(size_t)q * K_ + lane]                   = (int)(v & 0x1FFFull);  // nn_idx
        out[(size_t)NQ * K_ + (size_t)q * K_ + lane] = n;                     // center_idx
    }
}

extern "C" void kernel_launch(void* const* d_in, const int* in_sizes, int n_in,
                              void* d_out, int out_size, void* d_ws, size_t ws_size,
                              hipStream_t stream) {
    const float* x = (const float*)d_in[0];
    int* out = (int*)d_out;
    char* ws = (char*)d_ws;
    float*          nrm    = (float*)ws;                          //  64 KB @ 0
    float*          tau    = (float*)(ws + (64 << 10));           //  64 KB
    float*          eres   = (float*)(ws + (128 << 10));          //  64 KB
    float*          EH     = (float*)(ws + (192 << 10));          //  16 B
    unsigned short* cnt_pb = (unsigned short*)(ws + (256 << 10)); // 256 KB
    unsigned short* xh     = (unsigned short*)(ws + (1 << 20));   //   2 MB
    unsigned short* buf2   = (unsigned short*)(ws + (5 << 20));   // 10.5 MB (16384*8*40*2)
    float*          part   = (float*)(ws + (5 << 20));            //   8 MB, ALIASES buf2:
    // part is written by tau_p and fully consumed by tau_m BEFORE filter_k writes buf2.

    hipLaunchKernelGGL(split_k,  dim3(1024), dim3(256), 0, stream, x, xh, nrm, eres);
    hipLaunchKernelGGL(red_k,    dim3(2),    dim3(256), 0, stream, nrm, eres, EH);
    hipLaunchKernelGGL(tau_p,    dim3(512),  dim3(256), 0, stream, xh, nrm, part);
    hipLaunchKernelGGL(tau_m,    dim3(256),  dim3(64),  0, stream, part, nrm, eres, EH, tau);
    hipLaunchKernelGGL(filter_k, dim3(1024), dim3(256), 0, stream, xh, nrm, tau, cnt_pb, buf2);
    hipLaunchKernelGGL(rerank_k, dim3(4096), dim3(256), 0, stream, x, cnt_pb, buf2, out);
}

// Round 12
// 180.936 us; speedup vs baseline: 2.4141x; 1.0949x over previous
//
#include <hip/hip_runtime.h>
#include <stdint.h>

// KNN K=16 over x (B=2, N=8192, D=64) f32. Output int32 (2,B,N,K): nn_idx, center_idx.
// Pipeline: split_k -> red_k -> tau_p (MFMA min-ladders over 4096-sample) -> tau_m
// -> filter_k (MFMA filter, 256q x 1024m blocks, barrier-free gather streaming)
// -> rerank_k (exact f64, single round ~always).
// LESSONS LOG (filter_k):
//  R7: prefetch + full unroll -> ~270 VGPR demand -> 425 MB scratch spill. NO unroll.
//  R8: prefetch rolled still spilled ~5 dwords/iter (87 MB). NO reg prefetch.
//  R9: q-tile 64 / 2x blocks: duration EXACTLY 2x -> dur tracks TOTAL B-gather
//      work through L2/TCP (FETCH/WRITE unchanged -> L2-resident, not HBM).
//  R11: LDS-staged B + 16 barriers: TCP work down but barrier drains dominate
//      (16 MFMAs vs 2x ~300cyc vmcnt(0) drains per chunk) -> 66 us. NO staging.
//  R12 (this): the only lever that cuts TOTAL gather work without touching the
//      proven loop: q-tile 128->256 (512-thread blocks, 8 waves, SAME per-wave
//      tile/регs as R6). B work halves: (NQ/qtile)*N*redundancy.
// Bound: |key_approx - key_true| <= 2(n_q E + e_q H), E = max e, H = Nmax + E.
// tau = u16 + 2*slop provably keeps all true top-16 (pigeonhole: u16 = 16th
// smallest of 128 column-minima over the 4096-sample >= sample-d16 >= pop-d16).
constexpr int N_    = 8192;
constexpr int D_    = 64;
constexpr int K_    = 16;
constexpr int NQ    = 16384;          // 2*8192
constexpr int MS    = 8;              // m-superblocks per batch (1024 m each)
constexpr int CAPB  = 40;             // survivor cap per (query, superblock)

typedef __attribute__((ext_vector_type(8))) short bf16x8;
typedef __attribute__((ext_vector_type(4))) float f32x4;

template<int JN>
__device__ __forceinline__ void topk_insertf(float (&key)[JN], float nk) {
    if (nk < key[JN - 1]) {
        bool c[JN];
#pragma unroll
        for (int j = 0; j < JN; ++j) c[j] = nk < key[j];
#pragma unroll
        for (int j = JN - 1; j >= 1; --j)
            key[j] = c[j - 1] ? key[j - 1] : (c[j] ? nk : key[j]);
        key[0] = c[0] ? nk : key[0];
    }
}

__device__ __forceinline__ unsigned short bf16_rne(float f) {
    uint32_t u = __float_as_uint(f);
    return (unsigned short)((u + 0x7FFFu + ((u >> 16) & 1u)) >> 16);   // no NaN in data
}

// K1: bf16 hi split + true squared norms + residual norms. 16 lanes/row. grid=1024.
__global__ void __launch_bounds__(256) split_k(const float* __restrict__ x,
                                               unsigned short* __restrict__ xh,
                                               float* __restrict__ nrm,
                                               float* __restrict__ eres) {
    const int t = blockIdx.x * 256 + (int)threadIdx.x;    // one float4 per thread
    const int row = t >> 4, seg = t & 15;
    const float4 v = reinterpret_cast<const float4*>(x)[t];
    float f[4] = {v.x, v.y, v.z, v.w};
    unsigned short h[4];
    float sq = 0.f, esq = 0.f;
#pragma unroll
    for (int j = 0; j < 4; ++j) {
        sq = fmaf(f[j], f[j], sq);
        h[j] = bf16_rne(f[j]);
        float hf = __uint_as_float((uint32_t)h[j] << 16);
        float r  = f[j] - hf;
        esq = fmaf(r, r, esq);
    }
    sq  += __shfl_xor(sq, 1, 16);  sq  += __shfl_xor(sq, 2, 16);
    sq  += __shfl_xor(sq, 4, 16);  sq  += __shfl_xor(sq, 8, 16);
    esq += __shfl_xor(esq, 1, 16); esq += __shfl_xor(esq, 2, 16);
    esq += __shfl_xor(esq, 4, 16); esq += __shfl_xor(esq, 8, 16);
    if (seg == 0) { nrm[row] = sq; eres[row] = sqrtf(esq); }
    ushort4 hv = {h[0], h[1], h[2], h[3]};
    reinterpret_cast<ushort4*>(xh)[t] = hv;
}

// K1b: per-batch maxima: EH[b] = {Nmax, Emax} (inflated for f32 rounding). grid=2.
__global__ void __launch_bounds__(256) red_k(const float* __restrict__ nrm,
                                             const float* __restrict__ eres,
                                             float* __restrict__ EH) {
    __shared__ float mbuf[8];
    const int b = (int)blockIdx.x, tid = (int)threadIdx.x;
    float mn = 0.f, me = 0.f;
    for (int i = tid; i < N_; i += 256) {
        mn = fmaxf(mn, nrm[b * N_ + i]);
        me = fmaxf(me, eres[b * N_ + i]);
    }
#pragma unroll
    for (int s = 1; s < 64; s <<= 1) {
        mn = fmaxf(mn, __shfl_xor(mn, s, 64));
        me = fmaxf(me, __shfl_xor(me, s, 64));
    }
    const int w = tid >> 6;
    if ((tid & 63) == 0) { mbuf[w * 2] = mn; mbuf[w * 2 + 1] = me; }
    __syncthreads();
    if (tid == 0) {
        for (int i = 1; i < 4; ++i) {
            mn = fmaxf(mn, mbuf[i * 2]); me = fmaxf(me, mbuf[i * 2 + 1]);
        }
        EH[b * 2]     = sqrtf(mn) * 1.0002f + 1e-6f;      // Nmax upper bound
        EH[b * 2 + 1] = me * 1.0002f + 1e-7f;             // Emax upper bound
    }
}

// K2a: MFMA tau partials over a 4096-sample (R6-proven form, NO prefetch).
// Block = 128q x 1024 samples (quarter sh), 16 chunks of 64.
// grid = 128 q-tiles x 4 quarters = 512.
__global__ void __launch_bounds__(256, 4) tau_p(const unsigned short* __restrict__ xh,
                                                const float* __restrict__ nrm,
                                                float* __restrict__ part) {
    __shared__ alignas(16) float nrmS[1024];                // 4 KB sample norms
    const int tid = (int)threadIdx.x;
    const int bid = (int)blockIdx.x;
    const int qt  = bid >> 2, sh = bid & 3;
    const int q0g = qt * 128;
    const int b   = q0g >> 13;                              // uniform (128 | 8192)
    const int q0l = q0g & (N_ - 1);
    const int s0  = sh * 1024;
    const unsigned short* __restrict__ xhb = xh + (size_t)b * N_ * D_;
    const float* __restrict__ nb = nrm + b * N_;
    const int w = tid >> 6, lane = tid & 63;
    const int wq = w >> 1, wm = w & 1;                      // 64q x 32s wave subtile
    const int l15 = lane & 15, quad = lane >> 4;

    *(float4*)(nrmS + tid * 4) = *(const float4*)(nb + s0 + tid * 4);

    bf16x8 Af[2][4];                                        // A frags from global
#pragma unroll
    for (int half = 0; half < 2; ++half) {
        const int eo = (half * 4 + quad) * 8;               // element offset in row
#pragma unroll
        for (int tm = 0; tm < 4; ++tm)
            Af[half][tm] = *(const bf16x8*)(xhb + (size_t)(q0l + wq * 64 + tm * 16 + l15) * D_ + eo);
    }
    float lad[16];
#pragma unroll
    for (int j = 0; j < 16; ++j) lad[j] = __builtin_inff();
    __syncthreads();                                        // nrmS visible

    for (int mc = 0; mc < 16; ++mc) {
        const unsigned short* Bbase = xhb + (size_t)(s0 + mc * 64) * D_;
        bf16x8 Bf[2][2];                                    // B frags from global (coalesced lines)
#pragma unroll
        for (int half = 0; half < 2; ++half) {
            const int eo = (half * 4 + quad) * 8;
#pragma unroll
            for (int tn = 0; tn < 2; ++tn)
                Bf[half][tn] = *(const bf16x8*)(Bbase + (size_t)(wm * 32 + tn * 16 + l15) * D_ + eo);
        }
        f32x4 acc[4][2] = {};
#pragma unroll
        for (int half = 0; half < 2; ++half)
#pragma unroll
            for (int tm = 0; tm < 4; ++tm)
#pragma unroll
                for (int tn = 0; tn < 2; ++tn)
                    acc[tm][tn] = __builtin_amdgcn_mfma_f32_16x16x32_bf16(Af[half][tm], Bf[half][tn], acc[tm][tn], 0, 0, 0);
        // epilogue: C/D col=lane&15 (sample), row=quad*4+reg (q); depth-1 min
#pragma unroll
        for (int tn = 0; tn < 2; ++tn) {
            const float nm = nrmS[mc * 64 + wm * 32 + tn * 16 + l15];
#pragma unroll
            for (int tm = 0; tm < 4; ++tm)
#pragma unroll
                for (int reg = 0; reg < 4; ++reg)
                    lad[tm * 4 + reg] = fminf(lad[tm * 4 + reg],
                                              fmaf(-2.f, acc[tm][tn][reg], nm));
        }
    }
    // part[q][128]: offset = sh*32 + wm*16 + l15
#pragma unroll
    for (int tm = 0; tm < 4; ++tm)
#pragma unroll
        for (int reg = 0; reg < 4; ++reg) {
            const int q = q0g + wq * 64 + tm * 16 + quad * 4 + reg;
            part[(size_t)q * 128 + sh * 32 + wm * 16 + l15] = lad[tm * 4 + reg];
        }
}

// K2b: merge 128 partials/query -> tau with provable slop. grid = NQ/64 = 256.
__global__ void __launch_bounds__(64) tau_m(const float* __restrict__ part,
                                            const float* __restrict__ nrm,
                                            const float* __restrict__ eres,
                                            const float* __restrict__ EH,
                                            float* __restrict__ tau) {
    const int q = blockIdx.x * 64 + (int)threadIdx.x;
    const int b = q >> 13;
    const float4* p = reinterpret_cast<const float4*>(part + (size_t)q * 128);
    float key[K_];
#pragma unroll
    for (int j = 0; j < K_; ++j) key[j] = __builtin_inff();
    for (int i = 0; i < 32; ++i) {
        float4 v = p[i];
        topk_insertf<K_>(key, v.x); topk_insertf<K_>(key, v.y);
        topk_insertf<K_>(key, v.z); topk_insertf<K_>(key, v.w);
    }
    const float Nmax = EH[b * 2], Emax = EH[b * 2 + 1];
    const float H = Nmax + Emax;                            // >= max ||xh_m||
    const float nq = sqrtf(nrm[q]) * 1.0001f, eq = eres[q];
    tau[q] = key[15] + 4.f * (nq * Emax + eq * H) + 6e-3f;  // 2*s_q + f32 fudge
}

// K3: MFMA filter, BARRIER-FREE streaming (R6 loop), 256q x 1024m blocks.
// 512 threads = 8 waves (4 wq x 2 wm); per-wave tile IDENTICAL to R6
// (Af[2][4], acc[4][2], ~64 VGPR). Total B-gather work halves vs R6:
// (NQ/256) x N x 2(wm) line work. grid = 2*32*8 = 512 blocks (2/CU).
__global__ void __launch_bounds__(512, 4) filter_k(const unsigned short* __restrict__ xh,
                                                   const float* __restrict__ nrm,
                                                   const float* __restrict__ tau,
                                                   unsigned short* __restrict__ cnt_pb,
                                                   unsigned short* __restrict__ buf2) {
    __shared__ alignas(16) float nrmS[1024];                // 4 KB superblock norms
    __shared__ unsigned short lists[256 * CAPB];            // 20 KB
    __shared__ unsigned int cntL[256];
    const int tid = (int)threadIdx.x;
    const int bid = (int)blockIdx.x;
    const int b  = bid >> 8;
    const int qt = (bid >> 3) & 31;
    const int ms = bid & 7;
    const int q0 = qt * 256;
    const unsigned short* __restrict__ xhb = xh + (size_t)b * N_ * D_;
    const float* __restrict__ nb = nrm + b * N_;
    const int w = tid >> 6, lane = tid & 63;
    const int wq = w >> 1, wm = w & 1;                      // 64q x 32m wave subtile
    const int l15 = lane & 15, quad = lane >> 4;

    if (tid < 256) {
        *(float4*)(nrmS + tid * 4) = *(const float4*)(nb + ms * 1024 + tid * 4);
        cntL[tid] = 0;
    }

    bf16x8 Af[2][4];                                        // A frags from global
#pragma unroll
    for (int half = 0; half < 2; ++half) {
        const int eo = (half * 4 + quad) * 8;
#pragma unroll
        for (int tm = 0; tm < 4; ++tm)
            Af[half][tm] = *(const bf16x8*)(xhb + (size_t)(q0 + wq * 64 + tm * 16 + l15) * D_ + eo);
    }
    f32x4 t4v[4];
#pragma unroll
    for (int tm = 0; tm < 4; ++tm)
        t4v[tm] = *(const f32x4*)(tau + (b << 13) + q0 + wq * 64 + tm * 16 + quad * 4);
    __syncthreads();                                        // nrmS + cntL visible

    for (int mc = 0; mc < 16; ++mc) {
        const unsigned short* Bbase = xhb + (size_t)(ms * 1024 + mc * 64) * D_;
        bf16x8 Bf[2][2];                                    // coalesced line gathers
#pragma unroll
        for (int half = 0; half < 2; ++half) {
            const int eo = (half * 4 + quad) * 8;
#pragma unroll
            for (int tn = 0; tn < 2; ++tn)
                Bf[half][tn] = *(const bf16x8*)(Bbase + (size_t)(wm * 32 + tn * 16 + l15) * D_ + eo);
        }
        f32x4 acc[4][2] = {};
#pragma unroll
        for (int half = 0; half < 2; ++half)
#pragma unroll
            for (int tm = 0; tm < 4; ++tm)
#pragma unroll
                for (int tn = 0; tn < 2; ++tn)
                    acc[tm][tn] = __builtin_amdgcn_mfma_f32_16x16x32_bf16(Af[half][tm], Bf[half][tn], acc[tm][tn], 0, 0, 0);
        // epilogue: C/D col=lane&15 (m), row=quad*4+reg (q); accept key <= tau
#pragma unroll
        for (int tn = 0; tn < 2; ++tn) {
            const int mloc = mc * 64 + wm * 32 + tn * 16 + l15;
            const float nm = nrmS[mloc];
            const unsigned short mid = (unsigned short)(ms * 1024 + mloc);
#pragma unroll
            for (int tm = 0; tm < 4; ++tm)
#pragma unroll
                for (int reg = 0; reg < 4; ++reg) {
                    float keyf = fmaf(-2.f, acc[tm][tn][reg], nm);
                    if (keyf <= t4v[tm][reg]) {             // rare (~0.4%)
                        int ql = wq * 64 + tm * 16 + quad * 4 + reg;
                        unsigned pos = atomicAdd(&cntL[ql], 1u);    // LDS atomic
                        if (pos < CAPB) lists[ql * CAPB + pos] = mid;
                    }
                }
        }
    }
    __syncthreads();                                        // all waves' accepts visible
    if (tid < 256) {                                        // flush to fixed slots
        const int q = (b << 13) + q0 + tid;
        unsigned cn = cntL[tid]; cn = cn < CAPB ? cn : CAPB;
        cnt_pb[(size_t)q * MS + ms] = (unsigned short)cn;
        unsigned short* dst = buf2 + ((size_t)q * MS + ms) * CAPB;
        for (unsigned i = 0; i < cn; ++i) dst[i] = lists[tid * CAPB + i];
    }
}

// K4: exact f64 rerank, wave-per-query (32-VGPR latency-lean form; occupancy is
// the binding constraint). With the 4096-sample tau, total <= 64 for ~all
// queries -> single gather+f64+bitonic round. block 256 = 4 waves; grid = 4096.
__global__ void __launch_bounds__(256) rerank_k(const float* __restrict__ x,
                                                const unsigned short* __restrict__ cnt_pb,
                                                const unsigned short* __restrict__ buf2,
                                                int* __restrict__ out) {
    __shared__ float Qs[4 * 64];                           // 1 KB query rows
    __shared__ unsigned short ids[4 * MS * CAPB];          // 2.5 KB compacted survivors
    const int tid = (int)threadIdx.x;
    const int w = tid >> 6, lane = tid & 63;
    const int q = blockIdx.x * 4 + w;
    const int b = q >> 13, n = q & (N_ - 1);
    const float* __restrict__ xb = x + (size_t)b * N_ * D_;
    Qs[w * 64 + lane] = xb[(size_t)n * D_ + lane];

    int off[MS + 1]; off[0] = 0;                           // all lanes compute same
#pragma unroll
    for (int ms = 0; ms < MS; ++ms) {
        int c = (int)cnt_pb[(size_t)q * MS + ms]; c = c < CAPB ? c : CAPB;
        off[ms + 1] = off[ms] + c;
    }
    const int total = off[MS];                             // >= 16 guaranteed (true top-16 pass)
    for (int idx = lane; idx < total; idx += 64) {         // compact ids into LDS
        int ms = 0;
#pragma unroll
        for (int t = 1; t < MS; ++t) ms += (idx >= off[t]) ? 1 : 0;
        ids[(w * MS) * CAPB + idx] = buf2[((size_t)q * MS + ms) * CAPB + (idx - off[ms])];
    }
    __syncthreads();

    unsigned long long v = ~0ull;
    int consumed = 0;
    bool first = true;
    while (first || consumed < total) {
        const int myIdx = first ? lane : consumed + lane - 16;
        const bool take = (first || lane >= 16) && myIdx < total;
        unsigned long long nk = ~0ull;
        if (take) {
            const int id = (int)ids[(w * MS) * CAPB + myIdx];
            const float* __restrict__ crow = xb + (size_t)id * D_;
            double a0 = 0.0, a1 = 0.0, a2 = 0.0, a3 = 0.0;
#pragma unroll
            for (int j = 0; j < 16; ++j) {
                const float4 c  = *(const float4*)(crow + j * 4);        // per-lane gather
                const float4 qv = *(const float4*)(Qs + w * 64 + j * 4); // uniform -> broadcast
                double d0 = (double)qv.x - (double)c.x; a0 = fma(d0, d0, a0);
                double d1 = (double)qv.y - (double)c.y; a1 = fma(d1, d1, a1);
                double d2 = (double)qv.z - (double)c.z; a2 = fma(d2, d2, a2);
                double d3 = (double)qv.w - (double)c.w; a3 = fma(d3, d3, a3);
            }
            double s = (a0 + a1) + (a2 + a3);
            // s >= 0 -> f64 bits order-preserving; low 13 mantissa bits carry the id
            // for exact (dist, id) lexicographic compare (ties -> lower id).
            nk = ((unsigned long long)__double_as_longlong(s) & ~0x1FFFull) | (unsigned)id;
        }
        if (first || lane >= 16) v = nk;                   // lanes 0-15 keep running top-16
        // 64-lane bitonic sort ascending (21 steps)
#pragma unroll
        for (int k = 2; k <= 64; k <<= 1)
#pragma unroll
            for (int j = k >> 1; j > 0; j >>= 1) {
                unsigned long long o = __shfl_xor(v, j, 64);
                const bool keepmin = (((lane & k) == 0) == ((lane & j) == 0));
                unsigned long long mn = v < o ? v : o;
                unsigned long long mx = v < o ? o : v;
                v = keepmin ? mn : mx;
            }
        consumed += first ? 64 : 48;
        first = false;
    }
    if (lane < K_) {
        out[(size_t)q * K_ + lane]                   = (int)(v & 0x1FFFull);  // nn_idx
        out[(size_t)NQ * K_ + (size_t)q * K_ + lane] = n;                     // center_idx
    }
}

extern "C" void kernel_launch(void* const* d_in, const int* in_sizes, int n_in,
                              void* d_out, int out_size, void* d_ws, size_t ws_size,
                              hipStream_t stream) {
    const float* x = (const float*)d_in[0];
    int* out = (int*)d_out;
    char* ws = (char*)d_ws;
    float*          nrm    = (float*)ws;                          //  64 KB @ 0
    float*          tau    = (float*)(ws + (64 << 10));           //  64 KB
    float*          eres   = (float*)(ws + (128 << 10));          //  64 KB
    float*          EH     = (float*)(ws + (192 << 10));          //  16 B
    unsigned short* cnt_pb = (unsigned short*)(ws + (256 << 10)); // 256 KB
    unsigned short* xh     = (unsigned short*)(ws + (1 << 20));   //   2 MB
    unsigned short* buf2   = (unsigned short*)(ws + (5 << 20));   // 10.5 MB (16384*8*40*2)
    float*          part   = (float*)(ws + (5 << 20));            //   8 MB, ALIASES buf2:
    // part is written by tau_p and fully consumed by tau_m BEFORE filter_k writes buf2.

    hipLaunchKernelGGL(split_k,  dim3(1024), dim3(256), 0, stream, x, xh, nrm, eres);
    hipLaunchKernelGGL(red_k,    dim3(2),    dim3(256), 0, stream, nrm, eres, EH);
    hipLaunchKernelGGL(tau_p,    dim3(512),  dim3(256), 0, stream, xh, nrm, part);
    hipLaunchKernelGGL(tau_m,    dim3(256),  dim3(64),  0, stream, part, nrm, eres, EH, tau);
    hipLaunchKernelGGL(filter_k, dim3(512),  dim3(512), 0, stream, xh, nrm, tau, cnt_pb, buf2);
    hipLaunchKernelGGL(rerank_k, dim3(4096), dim3(256), 0, stream, x, cnt_pb, buf2, out);
}

// Round 13
// 165.647 us; speedup vs baseline: 2.6369x; 1.0923x over previous
//
#include <hip/hip_runtime.h>
#include <stdint.h>

// KNN K=16 over x (B=2, N=8192, D=64) f32. Output int32 (2,B,N,K): nn_idx, center_idx.
// Pipeline: split_k (bf16 hi split into TILE-PERMUTED layout + norms) -> red_k ->
// tau_p (MFMA min-ladders over 4096-sample) -> tau_m -> filter_k (MFMA filter,
// 256q x 1024m blocks, barrier-free streaming) -> rerank_k (exact f64).
// LESSONS LOG (filter_k):
//  R7: prefetch + full unroll -> 425 MB scratch spill. NO unroll.
//  R8: prefetch rolled still spilled (87 MB). NO reg prefetch.
//  R9/R12 scaling law: duration tracks B-FRAGMENT-LOAD INSTRUCTION count
//      (R9 2x instrs -> 2x dur; R12 half redundancy same instrs -> same dur).
//      Binder = per-instruction memory transactions: row-major fragment gather
//      = 16 scattered 64B transactions (128B stride, 50% line waste).
//  R11: LDS staging loses to barrier drains (16 MFMAs vs 2x300cyc). NO staging.
//  R13 (this): TILE-PERMUTED xh layout [row>>4][e>>3][row&15][e&7] makes every
//      A/B fragment load ONE CONTIGUOUS 1KB block (8x128B full transactions).
//      Same elements -> same lanes (address algebra identical), absmax 0.
// Bound: |key_approx - key_true| <= 2(n_q E + e_q H), E = max e, H = Nmax + E.
// tau = u16 + 2*slop provably keeps all true top-16 (pigeonhole over 4096-sample).
constexpr int N_    = 8192;
constexpr int D_    = 64;
constexpr int K_    = 16;
constexpr int NQ    = 16384;          // 2*8192
constexpr int MS    = 8;              // m-superblocks per batch (1024 m each)
constexpr int CAPB  = 40;             // survivor cap per (query, superblock)

typedef __attribute__((ext_vector_type(8))) short bf16x8;
typedef __attribute__((ext_vector_type(4))) float f32x4;

template<int JN>
__device__ __forceinline__ void topk_insertf(float (&key)[JN], float nk) {
    if (nk < key[JN - 1]) {
        bool c[JN];
#pragma unroll
        for (int j = 0; j < JN; ++j) c[j] = nk < key[j];
#pragma unroll
        for (int j = JN - 1; j >= 1; --j)
            key[j] = c[j - 1] ? key[j - 1] : (c[j] ? nk : key[j]);
        key[0] = c[0] ? nk : key[0];
    }
}

__device__ __forceinline__ unsigned short bf16_rne(float f) {
    uint32_t u = __float_as_uint(f);
    return (unsigned short)((u + 0x7FFFu + ((u >> 16) & 1u)) >> 16);   // no NaN in data
}

// K1: bf16 hi split + true squared norms + residual norms. 16 lanes/row. grid=1024.
// xh written TILE-PERMUTED: elem (row,e) -> (row>>4)*1024 + (e>>3)*128 + (row&15)*8 + (e&7).
// (row>>4 is GLOBAL: batch folds in since 512*1024 = 8192*64.)
__global__ void __launch_bounds__(256) split_k(const float* __restrict__ x,
                                               unsigned short* __restrict__ xh,
                                               float* __restrict__ nrm,
                                               float* __restrict__ eres) {
    const int t = blockIdx.x * 256 + (int)threadIdx.x;    // one float4 per thread
    const int row = t >> 4, seg = t & 15;                 // elements e = seg*4..seg*4+3
    const float4 v = reinterpret_cast<const float4*>(x)[t];
    float f[4] = {v.x, v.y, v.z, v.w};
    unsigned short h[4];
    float sq = 0.f, esq = 0.f;
#pragma unroll
    for (int j = 0; j < 4; ++j) {
        sq = fmaf(f[j], f[j], sq);
        h[j] = bf16_rne(f[j]);
        float hf = __uint_as_float((uint32_t)h[j] << 16);
        float r  = f[j] - hf;
        esq = fmaf(r, r, esq);
    }
    sq  += __shfl_xor(sq, 1, 16);  sq  += __shfl_xor(sq, 2, 16);
    sq  += __shfl_xor(sq, 4, 16);  sq  += __shfl_xor(sq, 8, 16);
    esq += __shfl_xor(esq, 1, 16); esq += __shfl_xor(esq, 2, 16);
    esq += __shfl_xor(esq, 4, 16); esq += __shfl_xor(esq, 8, 16);
    if (seg == 0) { nrm[row] = sq; eres[row] = sqrtf(esq); }
    ushort4 hv = {h[0], h[1], h[2], h[3]};
    const size_t po = (size_t)(row >> 4) * 1024 + (seg >> 1) * 128 + (row & 15) * 8 + (seg & 1) * 4;
    *reinterpret_cast<ushort4*>(xh + po) = hv;
}

// K1b: per-batch maxima: EH[b] = {Nmax, Emax} (inflated for f32 rounding). grid=2.
__global__ void __launch_bounds__(256) red_k(const float* __restrict__ nrm,
                                             const float* __restrict__ eres,
                                             float* __restrict__ EH) {
    __shared__ float mbuf[8];
    const int b = (int)blockIdx.x, tid = (int)threadIdx.x;
    float mn = 0.f, me = 0.f;
    for (int i = tid; i < N_; i += 256) {
        mn = fmaxf(mn, nrm[b * N_ + i]);
        me = fmaxf(me, eres[b * N_ + i]);
    }
#pragma unroll
    for (int s = 1; s < 64; s <<= 1) {
        mn = fmaxf(mn, __shfl_xor(mn, s, 64));
        me = fmaxf(me, __shfl_xor(me, s, 64));
    }
    const int w = tid >> 6;
    if ((tid & 63) == 0) { mbuf[w * 2] = mn; mbuf[w * 2 + 1] = me; }
    __syncthreads();
    if (tid == 0) {
        for (int i = 1; i < 4; ++i) {
            mn = fmaxf(mn, mbuf[i * 2]); me = fmaxf(me, mbuf[i * 2 + 1]);
        }
        EH[b * 2]     = sqrtf(mn) * 1.0002f + 1e-6f;      // Nmax upper bound
        EH[b * 2 + 1] = me * 1.0002f + 1e-7f;             // Emax upper bound
    }
}

// Fragment load from tile-permuted xh: rowblk's 16 rows, elems (half*4+quad)*8..+8
// for lane (quad,l15) = ONE contiguous 1KB block per wave per (half) pair.
__device__ __forceinline__ bf16x8 frag_ld(const unsigned short* __restrict__ xhb,
                                          int rowblk, int half, int quad, int l15) {
    return *(const bf16x8*)(xhb + (size_t)rowblk * 1024 + (half * 4 + quad) * 128 + l15 * 8);
}

// K2a: MFMA tau partials over a 4096-sample (permuted-layout loads).
// Block = 128q x 1024 samples (quarter sh), 16 chunks of 64. grid = 512.
__global__ void __launch_bounds__(256, 4) tau_p(const unsigned short* __restrict__ xh,
                                                const float* __restrict__ nrm,
                                                float* __restrict__ part) {
    __shared__ alignas(16) float nrmS[1024];                // 4 KB sample norms
    const int tid = (int)threadIdx.x;
    const int bid = (int)blockIdx.x;
    const int qt  = bid >> 2, sh = bid & 3;
    const int q0g = qt * 128;
    const int b   = q0g >> 13;                              // uniform (128 | 8192)
    const int q0l = q0g & (N_ - 1);
    const int s0  = sh * 1024;
    const unsigned short* __restrict__ xhb = xh + (size_t)b * N_ * D_;
    const float* __restrict__ nb = nrm + b * N_;
    const int w = tid >> 6, lane = tid & 63;
    const int wq = w >> 1, wm = w & 1;                      // 64q x 32s wave subtile
    const int l15 = lane & 15, quad = lane >> 4;

    *(float4*)(nrmS + tid * 4) = *(const float4*)(nb + s0 + tid * 4);

    bf16x8 Af[2][4];                                        // A frags (contiguous 1KB loads)
#pragma unroll
    for (int half = 0; half < 2; ++half)
#pragma unroll
        for (int tm = 0; tm < 4; ++tm)
            Af[half][tm] = frag_ld(xhb, (q0l >> 4) + wq * 4 + tm, half, quad, l15);
    float lad[16];
#pragma unroll
    for (int j = 0; j < 16; ++j) lad[j] = __builtin_inff();
    __syncthreads();                                        // nrmS visible

    for (int mc = 0; mc < 16; ++mc) {
        bf16x8 Bf[2][2];                                    // contiguous 1KB loads
#pragma unroll
        for (int half = 0; half < 2; ++half)
#pragma unroll
            for (int tn = 0; tn < 2; ++tn)
                Bf[half][tn] = frag_ld(xhb, sh * 64 + mc * 4 + wm * 2 + tn, half, quad, l15);
        f32x4 acc[4][2] = {};
#pragma unroll
        for (int half = 0; half < 2; ++half)
#pragma unroll
            for (int tm = 0; tm < 4; ++tm)
#pragma unroll
                for (int tn = 0; tn < 2; ++tn)
                    acc[tm][tn] = __builtin_amdgcn_mfma_f32_16x16x32_bf16(Af[half][tm], Bf[half][tn], acc[tm][tn], 0, 0, 0);
        // epilogue: C/D col=lane&15 (sample), row=quad*4+reg (q); depth-1 min
#pragma unroll
        for (int tn = 0; tn < 2; ++tn) {
            const float nm = nrmS[mc * 64 + wm * 32 + tn * 16 + l15];
#pragma unroll
            for (int tm = 0; tm < 4; ++tm)
#pragma unroll
                for (int reg = 0; reg < 4; ++reg)
                    lad[tm * 4 + reg] = fminf(lad[tm * 4 + reg],
                                              fmaf(-2.f, acc[tm][tn][reg], nm));
        }
    }
    // part[q][128]: offset = sh*32 + wm*16 + l15
#pragma unroll
    for (int tm = 0; tm < 4; ++tm)
#pragma unroll
        for (int reg = 0; reg < 4; ++reg) {
            const int q = q0g + wq * 64 + tm * 16 + quad * 4 + reg;
            part[(size_t)q * 128 + sh * 32 + wm * 16 + l15] = lad[tm * 4 + reg];
        }
}

// K2b: merge 128 partials/query -> tau with provable slop. grid = NQ/64 = 256.
__global__ void __launch_bounds__(64) tau_m(const float* __restrict__ part,
                                            const float* __restrict__ nrm,
                                            const float* __restrict__ eres,
                                            const float* __restrict__ EH,
                                            float* __restrict__ tau) {
    const int q = blockIdx.x * 64 + (int)threadIdx.x;
    const int b = q >> 13;
    const float4* p = reinterpret_cast<const float4*>(part + (size_t)q * 128);
    float key[K_];
#pragma unroll
    for (int j = 0; j < K_; ++j) key[j] = __builtin_inff();
    for (int i = 0; i < 32; ++i) {
        float4 v = p[i];
        topk_insertf<K_>(key, v.x); topk_insertf<K_>(key, v.y);
        topk_insertf<K_>(key, v.z); topk_insertf<K_>(key, v.w);
    }
    const float Nmax = EH[b * 2], Emax = EH[b * 2 + 1];
    const float H = Nmax + Emax;                            // >= max ||xh_m||
    const float nq = sqrtf(nrm[q]) * 1.0001f, eq = eres[q];
    tau[q] = key[15] + 4.f * (nq * Emax + eq * H) + 6e-3f;  // 2*s_q + f32 fudge
}

// K3: MFMA filter, BARRIER-FREE streaming, 256q x 1024m blocks (R12 geometry),
// permuted-layout fragment loads (contiguous 1KB per instr). 512 threads =
// 8 waves (4 wq x 2 wm); per-wave tile Af[2][4]/acc[4][2]. grid = 512 (2/CU).
__global__ void __launch_bounds__(512, 4) filter_k(const unsigned short* __restrict__ xh,
                                                   const float* __restrict__ nrm,
                                                   const float* __restrict__ tau,
                                                   unsigned short* __restrict__ cnt_pb,
                                                   unsigned short* __restrict__ buf2) {
    __shared__ alignas(16) float nrmS[1024];                // 4 KB superblock norms
    __shared__ unsigned short lists[256 * CAPB];            // 20 KB
    __shared__ unsigned int cntL[256];
    const int tid = (int)threadIdx.x;
    const int bid = (int)blockIdx.x;
    const int b  = bid >> 8;
    const int qt = (bid >> 3) & 31;
    const int ms = bid & 7;
    const int q0 = qt * 256;
    const unsigned short* __restrict__ xhb = xh + (size_t)b * N_ * D_;
    const float* __restrict__ nb = nrm + b * N_;
    const int w = tid >> 6, lane = tid & 63;
    const int wq = w >> 1, wm = w & 1;                      // 64q x 32m wave subtile
    const int l15 = lane & 15, quad = lane >> 4;

    if (tid < 256) {
        *(float4*)(nrmS + tid * 4) = *(const float4*)(nb + ms * 1024 + tid * 4);
        cntL[tid] = 0;
    }

    bf16x8 Af[2][4];                                        // A frags (contiguous 1KB loads)
#pragma unroll
    for (int half = 0; half < 2; ++half)
#pragma unroll
        for (int tm = 0; tm < 4; ++tm)
            Af[half][tm] = frag_ld(xhb, qt * 16 + wq * 4 + tm, half, quad, l15);
    f32x4 t4v[4];
#pragma unroll
    for (int tm = 0; tm < 4; ++tm)
        t4v[tm] = *(const f32x4*)(tau + (b << 13) + q0 + wq * 64 + tm * 16 + quad * 4);
    __syncthreads();                                        // nrmS + cntL visible

    for (int mc = 0; mc < 16; ++mc) {
        bf16x8 Bf[2][2];                                    // contiguous 1KB loads
#pragma unroll
        for (int half = 0; half < 2; ++half)
#pragma unroll
            for (int tn = 0; tn < 2; ++tn)
                Bf[half][tn] = frag_ld(xhb, ms * 64 + mc * 4 + wm * 2 + tn, half, quad, l15);
        f32x4 acc[4][2] = {};
#pragma unroll
        for (int half = 0; half < 2; ++half)
#pragma unroll
            for (int tm = 0; tm < 4; ++tm)
#pragma unroll
                for (int tn = 0; tn < 2; ++tn)
                    acc[tm][tn] = __builtin_amdgcn_mfma_f32_16x16x32_bf16(Af[half][tm], Bf[half][tn], acc[tm][tn], 0, 0, 0);
        // epilogue: C/D col=lane&15 (m), row=quad*4+reg (q); accept key <= tau
#pragma unroll
        for (int tn = 0; tn < 2; ++tn) {
            const int mloc = mc * 64 + wm * 32 + tn * 16 + l15;
            const float nm = nrmS[mloc];
            const unsigned short mid = (unsigned short)(ms * 1024 + mloc);
#pragma unroll
            for (int tm = 0; tm < 4; ++tm)
#pragma unroll
                for (int reg = 0; reg < 4; ++reg) {
                    float keyf = fmaf(-2.f, acc[tm][tn][reg], nm);
                    if (keyf <= t4v[tm][reg]) {             // rare (~0.4%)
                        int ql = wq * 64 + tm * 16 + quad * 4 + reg;
                        unsigned pos = atomicAdd(&cntL[ql], 1u);    // LDS atomic
                        if (pos < CAPB) lists[ql * CAPB + pos] = mid;
                    }
                }
        }
    }
    __syncthreads();                                        // all waves' accepts visible
    if (tid < 256) {                                        // flush to fixed slots
        const int q = (b << 13) + q0 + tid;
        unsigned cn = cntL[tid]; cn = cn < CAPB ? cn : CAPB;
        cnt_pb[(size_t)q * MS + ms] = (unsigned short)cn;
        unsigned short* dst = buf2 + ((size_t)q * MS + ms) * CAPB;
        for (unsigned i = 0; i < cn; ++i) dst[i] = lists[tid * CAPB + i];
    }
}

// K4: exact f64 rerank, wave-per-query (32-VGPR latency-lean form). With the
// 4096-sample tau, total <= 64 ~always -> single gather+f64+bitonic round.
// block 256 = 4 waves; grid = 4096.
__global__ void __launch_bounds__(256) rerank_k(const float* __restrict__ x,
                                                const unsigned short* __restrict__ cnt_pb,
                                                const unsigned short* __restrict__ buf2,
                                                int* __restrict__ out) {
    __shared__ float Qs[4 * 64];                           // 1 KB query rows
    __shared__ unsigned short ids[4 * MS * CAPB];          // 2.5 KB compacted survivors
    const int tid = (int)threadIdx.x;
    const int w = tid >> 6, lane = tid & 63;
    const int q = blockIdx.x * 4 + w;
    const int b = q >> 13, n = q & (N_ - 1);
    const float* __restrict__ xb = x + (size_t)b * N_ * D_;
    Qs[w * 64 + lane] = xb[(size_t)n * D_ + lane];

    int off[MS + 1]; off[0] = 0;                           // all lanes compute same
#pragma unroll
    for (int ms = 0; ms < MS; ++ms) {
        int c = (int)cnt_pb[(size_t)q * MS + ms]; c = c < CAPB ? c : CAPB;
        off[ms + 1] = off[ms] + c;
    }
    const int total = off[MS];                             // >= 16 guaranteed (true top-16 pass)
    for (int idx = lane; idx < total; idx += 64) {         // compact ids into LDS
        int ms = 0;
#pragma unroll
        for (int t = 1; t < MS; ++t) ms += (idx >= off[t]) ? 1 : 0;
        ids[(w * MS) * CAPB + idx] = buf2[((size_t)q * MS + ms) * CAPB + (idx - off[ms])];
    }
    __syncthreads();

    unsigned long long v = ~0ull;
    int consumed = 0;
    bool first = true;
    while (first || consumed < total) {
        const int myIdx = first ? lane : consumed + lane - 16;
        const bool take = (first || lane >= 16) && myIdx < total;
        unsigned long long nk = ~0ull;
        if (take) {
            const int id = (int)ids[(w * MS) * CAPB + myIdx];
            const float* __restrict__ crow = xb + (size_t)id * D_;
            double a0 = 0.0, a1 = 0.0, a2 = 0.0, a3 = 0.0;
#pragma unroll
            for (int j = 0; j < 16; ++j) {
                const float4 c  = *(const float4*)(crow + j * 4);        // per-lane gather
                const float4 qv = *(const float4*)(Qs + w * 64 + j * 4); // uniform -> broadcast
                double d0 = (double)qv.x - (double)c.x; a0 = fma(d0, d0, a0);
                double d1 = (double)qv.y - (double)c.y; a1 = fma(d1, d1, a1);
                double d2 = (double)qv.z - (double)c.z; a2 = fma(d2, d2, a2);
                double d3 = (double)qv.w - (double)c.w; a3 = fma(d3, d3, a3);
            }
            double s = (a0 + a1) + (a2 + a3);
            // s >= 0 -> f64 bits order-preserving; low 13 mantissa bits carry the id
            // for exact (dist, id) lexicographic compare (ties -> lower id).
            nk = ((unsigned long long)__double_as_longlong(s) & ~0x1FFFull) | (unsigned)id;
        }
        if (first || lane >= 16) v = nk;                   // lanes 0-15 keep running top-16
        // 64-lane bitonic sort ascending (21 steps)
#pragma unroll
        for (int k = 2; k <= 64; k <<= 1)
#pragma unroll
            for (int j = k >> 1; j > 0; j >>= 1) {
                unsigned long long o = __shfl_xor(v, j, 64);
                const bool keepmin = (((lane & k) == 0) == ((lane & j) == 0));
                unsigned long long mn = v < o ? v : o;
                unsigned long long mx = v < o ? o : v;
                v = keepmin ? mn : mx;
            }
        consumed += first ? 64 : 48;
        first = false;
    }
    if (lane < K_) {
        out[(size_t)q * K_ + lane]                   = (int)(v & 0x1FFFull);  // nn_idx
        out[(size_t)NQ * K_ + (size_t)q * K_ + lane] = n;                     // center_idx
    }
}

extern "C" void kernel_launch(void* const* d_in, const int* in_sizes, int n_in,
                              void* d_out, int out_size, void* d_ws, size_t ws_size,
                              hipStream_t stream) {
    const float* x = (const float*)d_in[0];
    int* out = (int*)d_out;
    char* ws = (char*)d_ws;
    float*          nrm    = (float*)ws;                          //  64 KB @ 0
    float*          tau    = (float*)(ws + (64 << 10));           //  64 KB
    float*          eres   = (float*)(ws + (128 << 10));          //  64 KB
    float*          EH     = (float*)(ws + (192 << 10));          //  16 B
    unsigned short* cnt_pb = (unsigned short*)(ws + (256 << 10)); // 256 KB
    unsigned short* xh     = (unsigned short*)(ws + (1 << 20));   //   2 MB (tile-permuted)
    unsigned short* buf2   = (unsigned short*)(ws + (5 << 20));   // 10.5 MB (16384*8*40*2)
    float*          part   = (float*)(ws + (5 << 20));            //   8 MB, ALIASES buf2:
    // part is written by tau_p and fully consumed by tau_m BEFORE filter_k writes buf2.

    hipLaunchKernelGGL(split_k,  dim3(1024), dim3(256), 0, stream, x, xh, nrm, eres);
    hipLaunchKernelGGL(red_k,    dim3(2),    dim3(256), 0, stream, nrm, eres, EH);
    hipLaunchKernelGGL(tau_p,    dim3(512),  dim3(256), 0, stream, xh, nrm, part);
    hipLaunchKernelGGL(tau_m,    dim3(256),  dim3(64),  0, stream, part, nrm, eres, EH, tau);
    hipLaunchKernelGGL(filter_k, dim3(512),  dim3(512), 0, stream, xh, nrm, tau, cnt_pb, buf2);
    hipLaunchKernelGGL(rerank_k, dim3(4096), dim3(256), 0, stream, x, cnt_pb, buf2, out);
}

// Round 14
// 164.765 us; speedup vs baseline: 2.6511x; 1.0054x over previous
//
#include <hip/hip_runtime.h>
#include <stdint.h>

// KNN K=16 over x (B=2, N=8192, D=64) f32. Output int32 (2,B,N,K): nn_idx, center_idx.
// Pipeline: split_k (bf16 hi split into TILE-PERMUTED layout + norms) -> red_k ->
// tau_p (MFMA min-ladders over 4096-sample) -> tau_m -> filter_k (MFMA filter,
// 256q x 1024m blocks, barrier-free streaming) -> rerank_k (exact f64).
// LESSONS LOG:
//  R7: prefetch + full unroll -> 425 MB scratch spill. NO unroll.
//  R8: prefetch rolled still spilled (87 MB). NO reg prefetch.
//  R9/R12 scaling law: duration tracks B-FRAGMENT-LOAD INSTRUCTION count;
//      binder = per-instruction memory transactions (row-major gather =
//      16 scattered 64B transactions).
//  R11: LDS staging loses to barrier drains. NO staging.
//  R13: TILE-PERMUTED xh [row>>4][e>>3][row&15][e&7] -> every fragment load is
//      ONE contiguous 1KB block. filter_k 44->~27us, total 181->165.6. SHIPPED.
//  R14 (this): rerank_k de-serialization — __syncthreads was unnecessary (all
//      LDS segments wave-private), single-round id kept in REGISTER (skip LDS
//      roundtrip; LDS written only when total>64), cnt_pb as one ushort8 load.
// Bound: |key_approx - key_true| <= 2(n_q E + e_q H), E = max e, H = Nmax + E.
// tau = u16 + 2*slop provably keeps all true top-16 (pigeonhole over 4096-sample).
constexpr int N_    = 8192;
constexpr int D_    = 64;
constexpr int K_    = 16;
constexpr int NQ    = 16384;          // 2*8192
constexpr int MS    = 8;              // m-superblocks per batch (1024 m each)
constexpr int CAPB  = 40;             // survivor cap per (query, superblock)

typedef __attribute__((ext_vector_type(8))) short bf16x8;
typedef __attribute__((ext_vector_type(4))) float f32x4;
typedef __attribute__((ext_vector_type(8))) unsigned short u16x8;

template<int JN>
__device__ __forceinline__ void topk_insertf(float (&key)[JN], float nk) {
    if (nk < key[JN - 1]) {
        bool c[JN];
#pragma unroll
        for (int j = 0; j < JN; ++j) c[j] = nk < key[j];
#pragma unroll
        for (int j = JN - 1; j >= 1; --j)
            key[j] = c[j - 1] ? key[j - 1] : (c[j] ? nk : key[j]);
        key[0] = c[0] ? nk : key[0];
    }
}

__device__ __forceinline__ unsigned short bf16_rne(float f) {
    uint32_t u = __float_as_uint(f);
    return (unsigned short)((u + 0x7FFFu + ((u >> 16) & 1u)) >> 16);   // no NaN in data
}

// K1: bf16 hi split + true squared norms + residual norms. 16 lanes/row. grid=1024.
// xh written TILE-PERMUTED: elem (row,e) -> (row>>4)*1024 + (e>>3)*128 + (row&15)*8 + (e&7).
// (row>>4 is GLOBAL: batch folds in since 512*1024 = 8192*64.)
__global__ void __launch_bounds__(256) split_k(const float* __restrict__ x,
                                               unsigned short* __restrict__ xh,
                                               float* __restrict__ nrm,
                                               float* __restrict__ eres) {
    const int t = blockIdx.x * 256 + (int)threadIdx.x;    // one float4 per thread
    const int row = t >> 4, seg = t & 15;                 // elements e = seg*4..seg*4+3
    const float4 v = reinterpret_cast<const float4*>(x)[t];
    float f[4] = {v.x, v.y, v.z, v.w};
    unsigned short h[4];
    float sq = 0.f, esq = 0.f;
#pragma unroll
    for (int j = 0; j < 4; ++j) {
        sq = fmaf(f[j], f[j], sq);
        h[j] = bf16_rne(f[j]);
        float hf = __uint_as_float((uint32_t)h[j] << 16);
        float r  = f[j] - hf;
        esq = fmaf(r, r, esq);
    }
    sq  += __shfl_xor(sq, 1, 16);  sq  += __shfl_xor(sq, 2, 16);
    sq  += __shfl_xor(sq, 4, 16);  sq  += __shfl_xor(sq, 8, 16);
    esq += __shfl_xor(esq, 1, 16); esq += __shfl_xor(esq, 2, 16);
    esq += __shfl_xor(esq, 4, 16); esq += __shfl_xor(esq, 8, 16);
    if (seg == 0) { nrm[row] = sq; eres[row] = sqrtf(esq); }
    ushort4 hv = {h[0], h[1], h[2], h[3]};
    const size_t po = (size_t)(row >> 4) * 1024 + (seg >> 1) * 128 + (row & 15) * 8 + (seg & 1) * 4;
    *reinterpret_cast<ushort4*>(xh + po) = hv;
}

// K1b: per-batch maxima: EH[b] = {Nmax, Emax} (inflated for f32 rounding). grid=2.
__global__ void __launch_bounds__(256) red_k(const float* __restrict__ nrm,
                                             const float* __restrict__ eres,
                                             float* __restrict__ EH) {
    __shared__ float mbuf[8];
    const int b = (int)blockIdx.x, tid = (int)threadIdx.x;
    float mn = 0.f, me = 0.f;
    for (int i = tid; i < N_; i += 256) {
        mn = fmaxf(mn, nrm[b * N_ + i]);
        me = fmaxf(me, eres[b * N_ + i]);
    }
#pragma unroll
    for (int s = 1; s < 64; s <<= 1) {
        mn = fmaxf(mn, __shfl_xor(mn, s, 64));
        me = fmaxf(me, __shfl_xor(me, s, 64));
    }
    const int w = tid >> 6;
    if ((tid & 63) == 0) { mbuf[w * 2] = mn; mbuf[w * 2 + 1] = me; }
    __syncthreads();
    if (tid == 0) {
        for (int i = 1; i < 4; ++i) {
            mn = fmaxf(mn, mbuf[i * 2]); me = fmaxf(me, mbuf[i * 2 + 1]);
        }
        EH[b * 2]     = sqrtf(mn) * 1.0002f + 1e-6f;      // Nmax upper bound
        EH[b * 2 + 1] = me * 1.0002f + 1e-7f;             // Emax upper bound
    }
}

// Fragment load from tile-permuted xh: rowblk's 16 rows, elems (half*4+quad)*8..+8
// for lane (quad,l15) = ONE contiguous 1KB block per wave per (half) pair.
__device__ __forceinline__ bf16x8 frag_ld(const unsigned short* __restrict__ xhb,
                                          int rowblk, int half, int quad, int l15) {
    return *(const bf16x8*)(xhb + (size_t)rowblk * 1024 + (half * 4 + quad) * 128 + l15 * 8);
}

// K2a: MFMA tau partials over a 4096-sample (permuted-layout loads).
// Block = 128q x 1024 samples (quarter sh), 16 chunks of 64. grid = 512.
__global__ void __launch_bounds__(256, 4) tau_p(const unsigned short* __restrict__ xh,
                                                const float* __restrict__ nrm,
                                                float* __restrict__ part) {
    __shared__ alignas(16) float nrmS[1024];                // 4 KB sample norms
    const int tid = (int)threadIdx.x;
    const int bid = (int)blockIdx.x;
    const int qt  = bid >> 2, sh = bid & 3;
    const int q0g = qt * 128;
    const int b   = q0g >> 13;                              // uniform (128 | 8192)
    const int q0l = q0g & (N_ - 1);
    const int s0  = sh * 1024;
    const unsigned short* __restrict__ xhb = xh + (size_t)b * N_ * D_;
    const float* __restrict__ nb = nrm + b * N_;
    const int w = tid >> 6, lane = tid & 63;
    const int wq = w >> 1, wm = w & 1;                      // 64q x 32s wave subtile
    const int l15 = lane & 15, quad = lane >> 4;

    *(float4*)(nrmS + tid * 4) = *(const float4*)(nb + s0 + tid * 4);

    bf16x8 Af[2][4];                                        // A frags (contiguous 1KB loads)
#pragma unroll
    for (int half = 0; half < 2; ++half)
#pragma unroll
        for (int tm = 0; tm < 4; ++tm)
            Af[half][tm] = frag_ld(xhb, (q0l >> 4) + wq * 4 + tm, half, quad, l15);
    float lad[16];
#pragma unroll
    for (int j = 0; j < 16; ++j) lad[j] = __builtin_inff();
    __syncthreads();                                        // nrmS visible

    for (int mc = 0; mc < 16; ++mc) {
        bf16x8 Bf[2][2];                                    // contiguous 1KB loads
#pragma unroll
        for (int half = 0; half < 2; ++half)
#pragma unroll
            for (int tn = 0; tn < 2; ++tn)
                Bf[half][tn] = frag_ld(xhb, sh * 64 + mc * 4 + wm * 2 + tn, half, quad, l15);
        f32x4 acc[4][2] = {};
#pragma unroll
        for (int half = 0; half < 2; ++half)
#pragma unroll
            for (int tm = 0; tm < 4; ++tm)
#pragma unroll
                for (int tn = 0; tn < 2; ++tn)
                    acc[tm][tn] = __builtin_amdgcn_mfma_f32_16x16x32_bf16(Af[half][tm], Bf[half][tn], acc[tm][tn], 0, 0, 0);
        // epilogue: C/D col=lane&15 (sample), row=quad*4+reg (q); depth-1 min
#pragma unroll
        for (int tn = 0; tn < 2; ++tn) {
            const float nm = nrmS[mc * 64 + wm * 32 + tn * 16 + l15];
#pragma unroll
            for (int tm = 0; tm < 4; ++tm)
#pragma unroll
                for (int reg = 0; reg < 4; ++reg)
                    lad[tm * 4 + reg] = fminf(lad[tm * 4 + reg],
                                              fmaf(-2.f, acc[tm][tn][reg], nm));
        }
    }
    // part[q][128]: offset = sh*32 + wm*16 + l15
#pragma unroll
    for (int tm = 0; tm < 4; ++tm)
#pragma unroll
        for (int reg = 0; reg < 4; ++reg) {
            const int q = q0g + wq * 64 + tm * 16 + quad * 4 + reg;
            part[(size_t)q * 128 + sh * 32 + wm * 16 + l15] = lad[tm * 4 + reg];
        }
}

// K2b: merge 128 partials/query -> tau with provable slop. grid = NQ/64 = 256.
__global__ void __launch_bounds__(64) tau_m(const float* __restrict__ part,
                                            const float* __restrict__ nrm,
                                            const float* __restrict__ eres,
                                            const float* __restrict__ EH,
                                            float* __restrict__ tau) {
    const int q = blockIdx.x * 64 + (int)threadIdx.x;
    const int b = q >> 13;
    const float4* p = reinterpret_cast<const float4*>(part + (size_t)q * 128);
    float key[K_];
#pragma unroll
    for (int j = 0; j < K_; ++j) key[j] = __builtin_inff();
    for (int i = 0; i < 32; ++i) {
        float4 v = p[i];
        topk_insertf<K_>(key, v.x); topk_insertf<K_>(key, v.y);
        topk_insertf<K_>(key, v.z); topk_insertf<K_>(key, v.w);
    }
    const float Nmax = EH[b * 2], Emax = EH[b * 2 + 1];
    const float H = Nmax + Emax;                            // >= max ||xh_m||
    const float nq = sqrtf(nrm[q]) * 1.0001f, eq = eres[q];
    tau[q] = key[15] + 4.f * (nq * Emax + eq * H) + 6e-3f;  // 2*s_q + f32 fudge
}

// K3: MFMA filter, BARRIER-FREE streaming, 256q x 1024m blocks, permuted-layout
// fragment loads (contiguous 1KB per instr). 512 threads = 8 waves (4 wq x 2 wm);
// per-wave tile Af[2][4]/acc[4][2]. grid = 512 (2/CU).
__global__ void __launch_bounds__(512, 4) filter_k(const unsigned short* __restrict__ xh,
                                                   const float* __restrict__ nrm,
                                                   const float* __restrict__ tau,
                                                   unsigned short* __restrict__ cnt_pb,
                                                   unsigned short* __restrict__ buf2) {
    __shared__ alignas(16) float nrmS[1024];                // 4 KB superblock norms
    __shared__ unsigned short lists[256 * CAPB];            // 20 KB
    __shared__ unsigned int cntL[256];
    const int tid = (int)threadIdx.x;
    const int bid = (int)blockIdx.x;
    const int b  = bid >> 8;
    const int qt = (bid >> 3) & 31;
    const int ms = bid & 7;
    const int q0 = qt * 256;
    const unsigned short* __restrict__ xhb = xh + (size_t)b * N_ * D_;
    const float* __restrict__ nb = nrm + b * N_;
    const int w = tid >> 6, lane = tid & 63;
    const int wq = w >> 1, wm = w & 1;                      // 64q x 32m wave subtile
    const int l15 = lane & 15, quad = lane >> 4;

    if (tid < 256) {
        *(float4*)(nrmS + tid * 4) = *(const float4*)(nb + ms * 1024 + tid * 4);
        cntL[tid] = 0;
    }

    bf16x8 Af[2][4];                                        // A frags (contiguous 1KB loads)
#pragma unroll
    for (int half = 0; half < 2; ++half)
#pragma unroll
        for (int tm = 0; tm < 4; ++tm)
            Af[half][tm] = frag_ld(xhb, qt * 16 + wq * 4 + tm, half, quad, l15);
    f32x4 t4v[4];
#pragma unroll
    for (int tm = 0; tm < 4; ++tm)
        t4v[tm] = *(const f32x4*)(tau + (b << 13) + q0 + wq * 64 + tm * 16 + quad * 4);
    __syncthreads();                                        // nrmS + cntL visible

    for (int mc = 0; mc < 16; ++mc) {
        bf16x8 Bf[2][2];                                    // contiguous 1KB loads
#pragma unroll
        for (int half = 0; half < 2; ++half)
#pragma unroll
            for (int tn = 0; tn < 2; ++tn)
                Bf[half][tn] = frag_ld(xhb, ms * 64 + mc * 4 + wm * 2 + tn, half, quad, l15);
        f32x4 acc[4][2] = {};
#pragma unroll
        for (int half = 0; half < 2; ++half)
#pragma unroll
            for (int tm = 0; tm < 4; ++tm)
#pragma unroll
                for (int tn = 0; tn < 2; ++tn)
                    acc[tm][tn] = __builtin_amdgcn_mfma_f32_16x16x32_bf16(Af[half][tm], Bf[half][tn], acc[tm][tn], 0, 0, 0);
        // epilogue: C/D col=lane&15 (m), row=quad*4+reg (q); accept key <= tau
#pragma unroll
        for (int tn = 0; tn < 2; ++tn) {
            const int mloc = mc * 64 + wm * 32 + tn * 16 + l15;
            const float nm = nrmS[mloc];
            const unsigned short mid = (unsigned short)(ms * 1024 + mloc);
#pragma unroll
            for (int tm = 0; tm < 4; ++tm)
#pragma unroll
                for (int reg = 0; reg < 4; ++reg) {
                    float keyf = fmaf(-2.f, acc[tm][tn][reg], nm);
                    if (keyf <= t4v[tm][reg]) {             // rare (~0.4%)
                        int ql = wq * 64 + tm * 16 + quad * 4 + reg;
                        unsigned pos = atomicAdd(&cntL[ql], 1u);    // LDS atomic
                        if (pos < CAPB) lists[ql * CAPB + pos] = mid;
                    }
                }
        }
    }
    __syncthreads();                                        // all waves' accepts visible
    if (tid < 256) {                                        // flush to fixed slots
        const int q = (b << 13) + q0 + tid;
        unsigned cn = cntL[tid]; cn = cn < CAPB ? cn : CAPB;
        cnt_pb[(size_t)q * MS + ms] = (unsigned short)cn;
        unsigned short* dst = buf2 + ((size_t)q * MS + ms) * CAPB;
        for (unsigned i = 0; i < cn; ++i) dst[i] = lists[tid * CAPB + i];
    }
}

// K4: exact f64 rerank, wave-per-query, DE-SERIALIZED (R14):
//  - NO __syncthreads (Qs/ids segments are wave-private; wave-internal LDS
//    ordering is HW/compiler-guaranteed).
//  - single-round fast path: lane's candidate id stays in a REGISTER (idx==lane
//    during compaction); ids LDS written only when total > 64 (wave-uniform).
//  - cnt_pb read as ONE aligned ushort8 (16 B) instead of 8 scalar loads.
// block 256 = 4 waves = 4 queries; grid = NQ/4 = 4096.
__global__ void __launch_bounds__(256) rerank_k(const float* __restrict__ x,
                                                const unsigned short* __restrict__ cnt_pb,
                                                const unsigned short* __restrict__ buf2,
                                                int* __restrict__ out) {
    __shared__ float Qs[4 * 64];                           // 1 KB query rows (wave-private)
    __shared__ unsigned short ids[4 * MS * CAPB];          // 2.5 KB survivors (wave-private)
    const int tid = (int)threadIdx.x;
    const int w = tid >> 6, lane = tid & 63;
    const int q = blockIdx.x * 4 + w;
    const int b = q >> 13, n = q & (N_ - 1);
    const float* __restrict__ xb = x + (size_t)b * N_ * D_;
    Qs[w * 64 + lane] = xb[(size_t)n * D_ + lane];

    const u16x8 cv = *reinterpret_cast<const u16x8*>(cnt_pb + (size_t)q * MS);  // 16B, aligned
    int off[MS + 1]; off[0] = 0;                           // all lanes compute same
#pragma unroll
    for (int ms = 0; ms < MS; ++ms) {
        int c = (int)cv[ms]; c = c < CAPB ? c : CAPB;
        off[ms + 1] = off[ms] + c;
    }
    const int total = off[MS];                             // >= 16 guaranteed (true top-16 pass)
    int myid = 0;                                          // register fast path (idx == lane)
    for (int idx = lane; idx < total; idx += 64) {         // compact ids
        int ms = 0;
#pragma unroll
        for (int t = 1; t < MS; ++t) ms += (idx >= off[t]) ? 1 : 0;
        const int id = (int)buf2[((size_t)q * MS + ms) * CAPB + (idx - off[ms])];
        if (idx == lane) myid = id;
        if (total > 64) ids[(w * MS) * CAPB + idx] = (unsigned short)id;  // refill only
    }
    // no barrier: all LDS traffic above is same-wave; refill reads below are same-wave.

    unsigned long long v = ~0ull;
    int consumed = 0;
    bool first = true;
    while (first || consumed < total) {
        const int myIdx = first ? lane : consumed + lane - 16;
        const bool take = (first || lane >= 16) && myIdx < total;
        unsigned long long nk = ~0ull;
        if (take) {
            const int id = first ? myid : (int)ids[(w * MS) * CAPB + myIdx];
            const float* __restrict__ crow = xb + (size_t)id * D_;
            double a0 = 0.0, a1 = 0.0, a2 = 0.0, a3 = 0.0;
#pragma unroll
            for (int j = 0; j < 16; ++j) {
                const float4 c  = *(const float4*)(crow + j * 4);        // per-lane gather
                const float4 qv = *(const float4*)(Qs + w * 64 + j * 4); // uniform -> broadcast
                double d0 = (double)qv.x - (double)c.x; a0 = fma(d0, d0, a0);
                double d1 = (double)qv.y - (double)c.y; a1 = fma(d1, d1, a1);
                double d2 = (double)qv.z - (double)c.z; a2 = fma(d2, d2, a2);
                double d3 = (double)qv.w - (double)c.w; a3 = fma(d3, d3, a3);
            }
            double s = (a0 + a1) + (a2 + a3);
            // s >= 0 -> f64 bits order-preserving; low 13 mantissa bits carry the id
            // for exact (dist, id) lexicographic compare (ties -> lower id).
            nk = ((unsigned long long)__double_as_longlong(s) & ~0x1FFFull) | (unsigned)id;
        }
        if (first || lane >= 16) v = nk;                   // lanes 0-15 keep running top-16
        // 64-lane bitonic sort ascending (21 steps)
#pragma unroll
        for (int k = 2; k <= 64; k <<= 1)
#pragma unroll
            for (int j = k >> 1; j > 0; j >>= 1) {
                unsigned long long o = __shfl_xor(v, j, 64);
                const bool keepmin = (((lane & k) == 0) == ((lane & j) == 0));
                unsigned long long mn = v < o ? v : o;
                unsigned long long mx = v < o ? o : v;
                v = keepmin ? mn : mx;
            }
        consumed += first ? 64 : 48;
        first = false;
    }
    if (lane < K_) {
        out[(size_t)q * K_ + lane]                   = (int)(v & 0x1FFFull);  // nn_idx
        out[(size_t)NQ * K_ + (size_t)q * K_ + lane] = n;                     // center_idx
    }
}

extern "C" void kernel_launch(void* const* d_in, const int* in_sizes, int n_in,
                              void* d_out, int out_size, void* d_ws, size_t ws_size,
                              hipStream_t stream) {
    const float* x = (const float*)d_in[0];
    int* out = (int*)d_out;
    char* ws = (char*)d_ws;
    float*          nrm    = (float*)ws;                          //  64 KB @ 0
    float*          tau    = (float*)(ws + (64 << 10));           //  64 KB
    float*          eres   = (float*)(ws + (128 << 10));          //  64 KB
    float*          EH     = (float*)(ws + (192 << 10));          //  16 B
    unsigned short* cnt_pb = (unsigned short*)(ws + (256 << 10)); // 256 KB
    unsigned short* xh     = (unsigned short*)(ws + (1 << 20));   //   2 MB (tile-permuted)
    unsigned short* buf2   = (unsigned short*)(ws + (5 << 20));   // 10.5 MB (16384*8*40*2)
    float*          part   = (float*)(ws + (5 << 20));            //   8 MB, ALIASES buf2:
    // part is written by tau_p and fully consumed by tau_m BEFORE filter_k writes buf2.

    hipLaunchKernelGGL(split_k,  dim3(1024), dim3(256), 0, stream, x, xh, nrm, eres);
    hipLaunchKernelGGL(red_k,    dim3(2),    dim3(256), 0, stream, nrm, eres, EH);
    hipLaunchKernelGGL(tau_p,    dim3(512),  dim3(256), 0, stream, xh, nrm, part);
    hipLaunchKernelGGL(tau_m,    dim3(256),  dim3(64),  0, stream, part, nrm, eres, EH, tau);
    hipLaunchKernelGGL(filter_k, dim3(512),  dim3(512), 0, stream, xh, nrm, tau, cnt_pb, buf2);
    hipLaunchKernelGGL(rerank_k, dim3(4096), dim3(256), 0, stream, x, cnt_pb, buf2, out);
}